// Round 5
// baseline (2014.105 us; speedup 1.0000x reference)
//
#include <hip/hip_runtime.h>
#include <hip/hip_bf16.h>

#define N_NODES 50000
#define N_EDGES 800000
#define N_GRAPHS 64
#define SCAN_B 196   // ceil(N_NODES/256)

typedef unsigned short u16;
typedef short s16x8 __attribute__((ext_vector_type(8)));
typedef float f32x4 __attribute__((ext_vector_type(4)));

#define NEGBIG -3.0e38f

__device__ __forceinline__ float bf2f(u16 u) {
    union { unsigned int i; float f; } v; v.i = ((unsigned int)u) << 16; return v.f;
}
__device__ __forceinline__ u16 f2bf(float f) {
    union { float f; unsigned int i; } v; v.f = f;
    unsigned int i = v.i;
    unsigned int r = i + 0x7fffu + ((i >> 16) & 1u);
    return (u16)(r >> 16);
}
__device__ __forceinline__ float asfloat(unsigned int u) {
    union { unsigned int i; float f; } v; v.i = u; return v.f;
}

// ---------------- CSR build (by dst) ----------------
__global__ __launch_bounds__(256) void k_hist(const int* __restrict__ dst, int* __restrict__ deg) {
    int e = blockIdx.x * 256 + threadIdx.x;
    if (e < N_EDGES) atomicAdd(&deg[dst[e]], 1);
}

// phase A: per-block exclusive scan; rowptr holds local-exclusive, bsum holds block totals
__global__ __launch_bounds__(256) void k_scanA(const int* __restrict__ deg,
                                               int* __restrict__ rowptr, int* __restrict__ bsum) {
    int b = blockIdx.x, t = threadIdx.x;
    int i = b * 256 + t;
    int v = (i < N_NODES) ? deg[i] : 0;
    int orig = v;
    int lane = t & 63, w = t >> 6;
#pragma unroll
    for (int d = 1; d < 64; d <<= 1) {
        int u = __shfl_up(v, d);
        if (lane >= d) v += u;
    }
    __shared__ int wsum[4];
    if (lane == 63) wsum[w] = v;
    __syncthreads();
    int add = 0;
    for (int k = 0; k < w; k++) add += wsum[k];
    v += add;
    if (i < N_NODES) rowptr[i] = v - orig;
    if (t == 255) bsum[b] = v;
}

// phase B: 1 block scans the 196 block sums -> boff (exclusive)
__global__ __launch_bounds__(256) void k_scanB(const int* __restrict__ bsum, int* __restrict__ boff) {
    int t = threadIdx.x;
    int v = (t < SCAN_B) ? bsum[t] : 0;
    int orig = v;
    int lane = t & 63, w = t >> 6;
#pragma unroll
    for (int d = 1; d < 64; d <<= 1) {
        int u = __shfl_up(v, d);
        if (lane >= d) v += u;
    }
    __shared__ int wsum[4];
    if (lane == 63) wsum[w] = v;
    __syncthreads();
    int add = 0;
    for (int k = 0; k < w; k++) add += wsum[k];
    v += add;
    if (t < SCAN_B) boff[t] = v - orig;
}

// phase C: add block offsets; deg becomes the scatter cursor; write rowptr[N]
__global__ __launch_bounds__(256) void k_scanC(const int* __restrict__ boff,
                                               int* __restrict__ rowptr, int* __restrict__ deg) {
    int b = blockIdx.x, t = threadIdx.x;
    int i = b * 256 + t;
    if (i < N_NODES) {
        int val = rowptr[i] + boff[b];
        int d = deg[i];
        rowptr[i] = val;
        deg[i] = val;
        if (i == N_NODES - 1) rowptr[N_NODES] = val + d;
    }
}

__global__ __launch_bounds__(256) void k_scatter(const int* __restrict__ src, const int* __restrict__ dst,
                                                 const float* __restrict__ ew, int* __restrict__ cursor,
                                                 int* __restrict__ csr_src, float* __restrict__ csr_ew) {
    int e = blockIdx.x * 256 + threadIdx.x;
    if (e < N_EDGES) {
        int d = dst[e];
        int pos = atomicAdd(&cursor[d], 1);
        csr_src[pos] = src[e];
        csr_ew[pos] = ew[e];
    }
}

// ---------------- W (f32, [64][256]) -> Wt (bf16, [256 col][64 d]), LDS tile transpose ----------------
// 12 blocks: layer = b/4, 64-col tile ti = b%4
__global__ __launch_bounds__(256) void k_prep(const float* __restrict__ W1, const float* __restrict__ W2,
                                              const float* __restrict__ W3, u16* __restrict__ Wt) {
    int l = blockIdx.x >> 2, ti = blockIdx.x & 3;
    const float* W = (l == 0) ? W1 : (l == 1) ? W2 : W3;
    u16* o = Wt + (size_t)l * 64 * 256;
    __shared__ float tile[64][65];
    int t = threadIdx.x;
    for (int i = t; i < 64 * 64; i += 256) {
        int d = i >> 6, c = i & 63;
        tile[d][c] = W[d * 256 + ti * 64 + c];     // coalesced read
    }
    __syncthreads();
    for (int i = t; i < 64 * 64; i += 256) {
        int c = i >> 6, d = i & 63;
        o[(size_t)(ti * 64 + c) * 64 + d] = f2bf(tile[d][c]);   // coalesced write, stride-65 LDS col read
    }
}

// ---------------- x = concat(nfeats,names)*centrality; fused gap0 (softmax-no-max via atomics) ----------------
__global__ __launch_bounds__(256) void k_input(const float* __restrict__ nf, const float* __restrict__ nm,
                                               const float* __restrict__ cent, const float* __restrict__ Wg,
                                               const float* __restrict__ bg, const int* __restrict__ gid,
                                               u16* __restrict__ x,
                                               float* __restrict__ hgnum, float* __restrict__ hgden) {
    int node = blockIdx.x * 4 + (threadIdx.x >> 6);
    int lane = threadIdx.x & 63;
    float v = (lane < 48) ? nf[(size_t)node * 48 + lane] : nm[(size_t)node * 16 + lane - 48];
    float xf = v * cent[node];
    x[(size_t)node * 64 + lane] = f2bf(xf);
    float p = xf * Wg[lane];
#pragma unroll
    for (int mm = 1; mm < 64; mm <<= 1) p += __shfl_xor(p, mm);
    float ex = __expf(p + bg[0]);     // logits are O(0.1): no max-subtraction needed
    int g = gid[node];
    atomicAdd(&hgnum[g * 64 + lane], ex * xf);
    if (lane == 0) atomicAdd(&hgden[g], ex);
}

// ---------------- ft = X @ W via MFMA 16x16x32 bf16, epilogue computes el/er ----------------
// ft stored as [N][64 d][4 h] bf16 (dim-major, head-minor) for the agg gather.
__global__ __launch_bounds__(256) void k_ft(const u16* __restrict__ X, const u16* __restrict__ Wt,
                                            const float* __restrict__ al, const float* __restrict__ ar,
                                            u16* __restrict__ ft, float* __restrict__ el, float* __restrict__ er) {
    int w = threadIdx.x >> 6;      // wave = head (cols w*64..w*64+63)
    int lane = threadIdx.x & 63;
    int quad = lane >> 4, c = lane & 15;
    int n0 = blockIdx.x * 16;

    f32x4 acc[4];
#pragma unroll
    for (int t = 0; t < 4; t++) acc[t] = (f32x4){0.f, 0.f, 0.f, 0.f};

#pragma unroll
    for (int kh = 0; kh < 2; kh++) {
        s16x8 a = *(const s16x8*)(X + (size_t)(n0 + c) * 64 + kh * 32 + quad * 8);
#pragma unroll
        for (int t = 0; t < 4; t++) {
            int col = w * 64 + t * 16 + c;
            s16x8 b = *(const s16x8*)(Wt + (size_t)col * 64 + kh * 32 + quad * 8);
            acc[t] = __builtin_amdgcn_mfma_f32_16x16x32_bf16(a, b, acc[t], 0, 0, 0);
        }
    }

    float alv[4], arv[4];
#pragma unroll
    for (int t = 0; t < 4; t++) {
        alv[t] = al[w * 64 + t * 16 + c];
        arv[t] = ar[w * 64 + t * 16 + c];
    }
    float pel[4] = {0.f, 0.f, 0.f, 0.f}, per[4] = {0.f, 0.f, 0.f, 0.f};
#pragma unroll
    for (int t = 0; t < 4; t++) {
#pragma unroll
        for (int r = 0; r < 4; r++) {
            float v = acc[t][r];
            int node = n0 + quad * 4 + r;
            int d = t * 16 + c;
            ft[(size_t)node * 256 + d * 4 + w] = f2bf(v);
            pel[r] += v * alv[t];
            per[r] += v * arv[t];
        }
    }
#pragma unroll
    for (int r = 0; r < 4; r++) {
#pragma unroll
        for (int mm = 1; mm < 16; mm <<= 1) {
            pel[r] += __shfl_xor(pel[r], mm);
            per[r] += __shfl_xor(per[r], mm);
        }
    }
    if (c == 0) {
#pragma unroll
        for (int r = 0; r < 4; r++) {
            int node = n0 + quad * 4 + r;
            el[node * 4 + w] = pel[r];
            er[node * 4 + w] = per[r];
        }
    }
}

// ---------------- per-dst-node edge softmax + aggregation; fused gap (atomics) ----------------
__global__ __launch_bounds__(256) void k_agg(
    const u16* __restrict__ ft, const float4* __restrict__ el4, const float4* __restrict__ er4,
    const int* __restrict__ rowptr, const int* __restrict__ csr_src, const float* __restrict__ csr_ew,
    const float* __restrict__ bias, const float* __restrict__ Wg, const float* __restrict__ bg,
    const int* __restrict__ gid,
    u16* __restrict__ hout, float* __restrict__ hgnum, float* __restrict__ hgden) {
    int node = blockIdx.x * 4 + (threadIdx.x >> 6);
    int lane = threadIdx.x & 63;
    int beg = rowptr[node], end = rowptr[node + 1];
    float4 erv = er4[node];

    float m0 = NEGBIG, m1 = NEGBIG, m2 = NEGBIG, m3 = NEGBIG;
    float S0 = 0.f, S1 = 0.f, S2 = 0.f, S3 = 0.f;
    float a0 = 0.f, a1 = 0.f, a2 = 0.f, a3 = 0.f;

    for (int base = beg; base < end; base += 64) {
        int cnt = end - base; if (cnt > 64) cnt = 64;
        int sidx = 0; float w = 0.f;
        float e0 = NEGBIG, e1 = NEGBIG, e2 = NEGBIG, e3 = NEGBIG;
        if (lane < cnt) {
            sidx = csr_src[base + lane];
            w = csr_ew[base + lane];
            float4 elv = el4[sidx];
            float t0 = elv.x + erv.x, t1 = elv.y + erv.y, t2 = elv.z + erv.z, t3 = elv.w + erv.w;
            e0 = t0 > 0.f ? t0 : 0.2f * t0;
            e1 = t1 > 0.f ? t1 : 0.2f * t1;
            e2 = t2 > 0.f ? t2 : 0.2f * t2;
            e3 = t3 > 0.f ? t3 : 0.2f * t3;
        }
        float M0 = e0, M1 = e1, M2 = e2, M3 = e3;
#pragma unroll
        for (int mm = 1; mm < 64; mm <<= 1) {
            M0 = fmaxf(M0, __shfl_xor(M0, mm));
            M1 = fmaxf(M1, __shfl_xor(M1, mm));
            M2 = fmaxf(M2, __shfl_xor(M2, mm));
            M3 = fmaxf(M3, __shfl_xor(M3, mm));
        }
        float n0 = fmaxf(m0, M0), n1 = fmaxf(m1, M1), n2 = fmaxf(m2, M2), n3 = fmaxf(m3, M3);
        float al0 = __expf(m0 - n0), al1 = __expf(m1 - n1), al2 = __expf(m2 - n2), al3 = __expf(m3 - n3);
        S0 *= al0; S1 *= al1; S2 *= al2; S3 *= al3;
        a0 *= al0; a1 *= al1; a2 *= al2; a3 *= al3;
        m0 = n0; m1 = n1; m2 = n2; m3 = n3;
        float p0 = __expf(e0 - n0), p1 = __expf(e1 - n1), p2 = __expf(e2 - n2), p3 = __expf(e3 - n3);
        float s0 = p0, s1 = p1, s2 = p2, s3 = p3;
#pragma unroll
        for (int mm = 1; mm < 64; mm <<= 1) {
            s0 += __shfl_xor(s0, mm);
            s1 += __shfl_xor(s1, mm);
            s2 += __shfl_xor(s2, mm);
            s3 += __shfl_xor(s3, mm);
        }
        S0 += s0; S1 += s1; S2 += s2; S3 += s3;
        p0 *= w; p1 *= w; p2 *= w; p3 *= w;
        for (int k = 0; k < cnt; k++) {
            int sk = __shfl(sidx, k);
            float b0 = __shfl(p0, k), b1 = __shfl(p1, k), b2 = __shfl(p2, k), b3 = __shfl(p3, k);
            uint2 raw = *(const uint2*)(ft + (size_t)sk * 256 + lane * 4);
            a0 = fmaf(b0, asfloat(raw.x << 16), a0);
            a1 = fmaf(b1, asfloat(raw.x & 0xffff0000u), a1);
            a2 = fmaf(b2, asfloat(raw.y << 16), a2);
            a3 = fmaf(b3, asfloat(raw.y & 0xffff0000u), a3);
        }
    }
    float i0 = S0 > 0.f ? 1.f / S0 : 0.f;
    float i1 = S1 > 0.f ? 1.f / S1 : 0.f;
    float i2 = S2 > 0.f ? 1.f / S2 : 0.f;
    float i3 = S3 > 0.f ? 1.f / S3 : 0.f;
    float r0 = a0 * i0 + bias[lane];
    float r1 = a1 * i1 + bias[64 + lane];
    float r2 = a2 * i2 + bias[128 + lane];
    float r3 = a3 * i3 + bias[192 + lane];
    float o = (fmaxf(r0, 0.f) + fmaxf(r1, 0.f) + fmaxf(r2, 0.f) + fmaxf(r3, 0.f)) * 0.25f;
    hout[(size_t)node * 64 + lane] = f2bf(o);
    float pg = o * Wg[lane];
#pragma unroll
    for (int mm = 1; mm < 64; mm <<= 1) pg += __shfl_xor(pg, mm);
    float ex = __expf(pg + bg[0]);
    int g = gid[node];
    atomicAdd(&hgnum[g * 64 + lane], ex * o);
    if (lane == 0) atomicAdd(&hgden[g], ex);
}

// ---------------- LSTM (4 steps) + final linear + sigmoid: one block per batch elem ----------------
__global__ __launch_bounds__(256) void k_lstm(const float* __restrict__ hgnum, const float* __restrict__ hgden,
                                              const float* __restrict__ Wih, const float* __restrict__ Whh,
                                              const float* __restrict__ bih, const float* __restrict__ bhh,
                                              const float* __restrict__ Wc, const float* __restrict__ bc,
                                              float* __restrict__ out) {
    int b = blockIdx.x, t = threadIdx.x;
    __shared__ float h[64], c[64], G[256], xv[64], red[64];
    if (t < 64) { h[t] = 0.f; c[t] = 0.f; }
    __syncthreads();
    for (int step = 0; step < 4; step++) {
        if (t < 64) {
            float den = hgden[step * N_GRAPHS + b];
            xv[t] = (den > 0.f) ? hgnum[step * 4096 + b * 64 + t] / den : 0.f;
        }
        __syncthreads();
        float acc = bih[t] + bhh[t];
#pragma unroll 4
        for (int d = 0; d < 64; d++)
            acc += xv[d] * Wih[t * 64 + d] + h[d] * Whh[t * 64 + d];
        G[t] = acc;
        __syncthreads();
        if (t < 64) {
            float ig = 1.f / (1.f + __expf(-G[t]));
            float fg = 1.f / (1.f + __expf(-G[64 + t]));
            float gg = tanhf(G[128 + t]);
            float og = 1.f / (1.f + __expf(-G[192 + t]));
            float cn = fg * c[t] + ig * gg;
            c[t] = cn;
            h[t] = og * tanhf(cn);
        }
        __syncthreads();
    }
    if (t < 64) red[t] = h[t] * Wc[t];
    __syncthreads();
    if (t == 0) {
        float r = 0.f;
        for (int i = 0; i < 64; i++) r += red[i];
        r += bc[0];
        out[b] = 1.f / (1.f + __expf(-r));
    }
}

extern "C" void kernel_launch(void* const* d_in, const int* in_sizes, int n_in,
                              void* d_out, int out_size, void* d_ws, size_t ws_size,
                              hipStream_t stream) {
    const float* nf   = (const float*)d_in[0];
    const float* nm   = (const float*)d_in[1];
    const float* cent = (const float*)d_in[2];
    const float* ew   = (const float*)d_in[3];
    const int* src  = (const int*)d_in[4];
    const int* dst  = (const int*)d_in[5];
    const int* gid  = (const int*)d_in[6];
    const float* W[3]  = {(const float*)d_in[7],  (const float*)d_in[11], (const float*)d_in[15]};
    const float* al[3] = {(const float*)d_in[8],  (const float*)d_in[12], (const float*)d_in[16]};
    const float* ar[3] = {(const float*)d_in[9],  (const float*)d_in[13], (const float*)d_in[17]};
    const float* bb[3] = {(const float*)d_in[10], (const float*)d_in[14], (const float*)d_in[18]};
    const float* Wg[4] = {(const float*)d_in[19], (const float*)d_in[21], (const float*)d_in[23], (const float*)d_in[25]};
    const float* bg[4] = {(const float*)d_in[20], (const float*)d_in[22], (const float*)d_in[24], (const float*)d_in[26]};
    const float* Wih = (const float*)d_in[27];
    const float* Whh = (const float*)d_in[28];
    const float* bih = (const float*)d_in[29];
    const float* bhh = (const float*)d_in[30];
    const float* Wc  = (const float*)d_in[31];
    const float* bc  = (const float*)d_in[32];
    float* out = (float*)d_out;

    char* p = (char*)d_ws;
    size_t off = 0;
    auto A = [&](size_t bytes) -> char* {
        char* r = p + off;
        off += (bytes + 255) & ~(size_t)255;
        return r;
    };
    u16*   ftb     = (u16*)  A((size_t)N_NODES * 256 * 2);   // 25.6 MB
    u16*   nodebuf = (u16*)  A((size_t)N_NODES * 64 * 2);    // 6.4 MB
    int*   csr_src = (int*)  A((size_t)N_EDGES * 4);         // 3.2 MB
    float* csr_ew  = (float*)A((size_t)N_EDGES * 4);         // 3.2 MB
    float* el      = (float*)A((size_t)N_NODES * 4 * 4);
    float* er      = (float*)A((size_t)N_NODES * 4 * 4);
    int*   rowptr  = (int*)  A((size_t)(N_NODES + 1) * 4);
    // ---- zeroed region (one memset): deg | hgnum | hgden ----
    int*   deg     = (int*)  A((size_t)(N_NODES + 1) * 4);   // scatter cursor after scan
    float* hgnum   = (float*)A((size_t)4 * N_GRAPHS * 64 * 4);
    float* hgden   = (float*)A((size_t)4 * N_GRAPHS * 4);
    size_t zbytes  = (((size_t)(N_NODES + 1) * 4 + 255) & ~(size_t)255)
                   + (((size_t)4 * N_GRAPHS * 64 * 4 + 255) & ~(size_t)255)
                   + (((size_t)4 * N_GRAPHS * 4 + 255) & ~(size_t)255);
    // ---- end zeroed region ----
    int*   bsum    = (int*)  A((size_t)SCAN_B * 4);
    int*   boff    = (int*)  A((size_t)SCAN_B * 4);
    u16*   Wt      = (u16*)  A((size_t)3 * 64 * 256 * 2);

    hipMemsetAsync(deg, 0, zbytes, stream);
    k_hist<<<(N_EDGES + 255) / 256, 256, 0, stream>>>(dst, deg);
    k_scanA<<<SCAN_B, 256, 0, stream>>>(deg, rowptr, bsum);
    k_scanB<<<1, 256, 0, stream>>>(bsum, boff);
    k_scanC<<<SCAN_B, 256, 0, stream>>>(boff, rowptr, deg);
    k_scatter<<<(N_EDGES + 255) / 256, 256, 0, stream>>>(src, dst, ew, deg, csr_src, csr_ew);
    k_prep<<<12, 256, 0, stream>>>(W[0], W[1], W[2], Wt);

    k_input<<<N_NODES / 4, 256, 0, stream>>>(nf, nm, cent, Wg[0], bg[0], gid, nodebuf, hgnum, hgden);

    for (int l = 0; l < 3; l++) {
        k_ft<<<N_NODES / 16, 256, 0, stream>>>(nodebuf, Wt + (size_t)l * 64 * 256, al[l], ar[l], ftb, el, er);
        k_agg<<<N_NODES / 4, 256, 0, stream>>>(ftb, (const float4*)el, (const float4*)er, rowptr,
                                               csr_src, csr_ew, bb[l], Wg[l + 1], bg[l + 1], gid,
                                               nodebuf, hgnum + (size_t)(l + 1) * 4096, hgden + (size_t)(l + 1) * N_GRAPHS);
    }
    k_lstm<<<N_GRAPHS, 256, 0, stream>>>(hgnum, hgden, Wih, Whh, bih, bhh, Wc, bc, out);
}

// Round 6
// 749.681 us; speedup vs baseline: 2.6866x; 2.6866x over previous
//
#include <hip/hip_runtime.h>
#include <hip/hip_bf16.h>

#define N_NODES 50000
#define N_EDGES 800000
#define N_GRAPHS 64
#define SCAN_B 196   // ceil(N_NODES/256)

typedef unsigned short u16;
typedef short s16x8 __attribute__((ext_vector_type(8)));
typedef float f32x4 __attribute__((ext_vector_type(4)));

#define NEGBIG -3.0e38f

__device__ __forceinline__ float bf2f(u16 u) {
    union { unsigned int i; float f; } v; v.i = ((unsigned int)u) << 16; return v.f;
}
__device__ __forceinline__ u16 f2bf(float f) {
    union { float f; unsigned int i; } v; v.f = f;
    unsigned int i = v.i;
    unsigned int r = i + 0x7fffu + ((i >> 16) & 1u);
    return (u16)(r >> 16);
}
__device__ __forceinline__ float asfloat(unsigned int u) {
    union { unsigned int i; float f; } v; v.i = u; return v.f;
}

// ---------------- CSR build (by dst) ----------------
__global__ __launch_bounds__(256) void k_hist(const int* __restrict__ dst, int* __restrict__ deg) {
    int e = blockIdx.x * 256 + threadIdx.x;
    if (e < N_EDGES) atomicAdd(&deg[dst[e]], 1);
}

// phase A: per-block exclusive scan; rowptr holds local-exclusive, bsum holds block totals
__global__ __launch_bounds__(256) void k_scanA(const int* __restrict__ deg,
                                               int* __restrict__ rowptr, int* __restrict__ bsum) {
    int b = blockIdx.x, t = threadIdx.x;
    int i = b * 256 + t;
    int v = (i < N_NODES) ? deg[i] : 0;
    int orig = v;
    int lane = t & 63, w = t >> 6;
#pragma unroll
    for (int d = 1; d < 64; d <<= 1) {
        int u = __shfl_up(v, d);
        if (lane >= d) v += u;
    }
    __shared__ int wsum[4];
    if (lane == 63) wsum[w] = v;
    __syncthreads();
    int add = 0;
    for (int k = 0; k < w; k++) add += wsum[k];
    v += add;
    if (i < N_NODES) rowptr[i] = v - orig;
    if (t == 255) bsum[b] = v;
}

// phase B: 1 block scans the 196 block sums -> boff (exclusive)
__global__ __launch_bounds__(256) void k_scanB(const int* __restrict__ bsum, int* __restrict__ boff) {
    int t = threadIdx.x;
    int v = (t < SCAN_B) ? bsum[t] : 0;
    int orig = v;
    int lane = t & 63, w = t >> 6;
#pragma unroll
    for (int d = 1; d < 64; d <<= 1) {
        int u = __shfl_up(v, d);
        if (lane >= d) v += u;
    }
    __shared__ int wsum[4];
    if (lane == 63) wsum[w] = v;
    __syncthreads();
    int add = 0;
    for (int k = 0; k < w; k++) add += wsum[k];
    v += add;
    if (t < SCAN_B) boff[t] = v - orig;
}

// phase C: add block offsets; deg becomes the scatter cursor; write rowptr[N]
__global__ __launch_bounds__(256) void k_scanC(const int* __restrict__ boff,
                                               int* __restrict__ rowptr, int* __restrict__ deg) {
    int b = blockIdx.x, t = threadIdx.x;
    int i = b * 256 + t;
    if (i < N_NODES) {
        int val = rowptr[i] + boff[b];
        int d = deg[i];
        rowptr[i] = val;
        deg[i] = val;
        if (i == N_NODES - 1) rowptr[N_NODES] = val + d;
    }
}

__global__ __launch_bounds__(256) void k_scatter(const int* __restrict__ src, const int* __restrict__ dst,
                                                 const float* __restrict__ ew, int* __restrict__ cursor,
                                                 int* __restrict__ csr_src, float* __restrict__ csr_ew) {
    int e = blockIdx.x * 256 + threadIdx.x;
    if (e < N_EDGES) {
        int d = dst[e];
        int pos = atomicAdd(&cursor[d], 1);
        csr_src[pos] = src[e];
        csr_ew[pos] = ew[e];
    }
}

// ---------------- W (f32, [64][256]) -> Wt (bf16, [256 col][64 d]), LDS tile transpose ----------------
__global__ __launch_bounds__(256) void k_prep(const float* __restrict__ W1, const float* __restrict__ W2,
                                              const float* __restrict__ W3, u16* __restrict__ Wt) {
    int l = blockIdx.x >> 2, ti = blockIdx.x & 3;
    const float* W = (l == 0) ? W1 : (l == 1) ? W2 : W3;
    u16* o = Wt + (size_t)l * 64 * 256;
    __shared__ float tile[64][65];
    int t = threadIdx.x;
    for (int i = t; i < 64 * 64; i += 256) {
        int d = i >> 6, c = i & 63;
        tile[d][c] = W[d * 256 + ti * 64 + c];
    }
    __syncthreads();
    for (int i = t; i < 64 * 64; i += 256) {
        int c = i >> 6, d = i & 63;
        o[(size_t)(ti * 64 + c) * 64 + d] = f2bf(tile[d][c]);
    }
}

// ---------------- x = concat(nfeats,names)*centrality, fused gap0 gate logit ----------------
__global__ __launch_bounds__(256) void k_input(const float* __restrict__ nf, const float* __restrict__ nm,
                                               const float* __restrict__ cent, const float* __restrict__ Wg,
                                               const float* __restrict__ bg,
                                               u16* __restrict__ x, float* __restrict__ g) {
    int node = blockIdx.x * 4 + (threadIdx.x >> 6);
    int lane = threadIdx.x & 63;
    float v = (lane < 48) ? nf[(size_t)node * 48 + lane] : nm[(size_t)node * 16 + lane - 48];
    float xf = v * cent[node];
    x[(size_t)node * 64 + lane] = f2bf(xf);
    float p = xf * Wg[lane];
#pragma unroll
    for (int mm = 1; mm < 64; mm <<= 1) p += __shfl_xor(p, mm);
    if (lane == 0) g[node] = p + bg[0];
}

// ---------------- ft = X @ W via MFMA 16x16x32 bf16, epilogue computes el/er ----------------
__global__ __launch_bounds__(256) void k_ft(const u16* __restrict__ X, const u16* __restrict__ Wt,
                                            const float* __restrict__ al, const float* __restrict__ ar,
                                            u16* __restrict__ ft, float* __restrict__ el, float* __restrict__ er) {
    int w = threadIdx.x >> 6;
    int lane = threadIdx.x & 63;
    int quad = lane >> 4, c = lane & 15;
    int n0 = blockIdx.x * 16;

    f32x4 acc[4];
#pragma unroll
    for (int t = 0; t < 4; t++) acc[t] = (f32x4){0.f, 0.f, 0.f, 0.f};

#pragma unroll
    for (int kh = 0; kh < 2; kh++) {
        s16x8 a = *(const s16x8*)(X + (size_t)(n0 + c) * 64 + kh * 32 + quad * 8);
#pragma unroll
        for (int t = 0; t < 4; t++) {
            int col = w * 64 + t * 16 + c;
            s16x8 b = *(const s16x8*)(Wt + (size_t)col * 64 + kh * 32 + quad * 8);
            acc[t] = __builtin_amdgcn_mfma_f32_16x16x32_bf16(a, b, acc[t], 0, 0, 0);
        }
    }

    float alv[4], arv[4];
#pragma unroll
    for (int t = 0; t < 4; t++) {
        alv[t] = al[w * 64 + t * 16 + c];
        arv[t] = ar[w * 64 + t * 16 + c];
    }
    float pel[4] = {0.f, 0.f, 0.f, 0.f}, per[4] = {0.f, 0.f, 0.f, 0.f};
#pragma unroll
    for (int t = 0; t < 4; t++) {
#pragma unroll
        for (int r = 0; r < 4; r++) {
            float v = acc[t][r];
            int node = n0 + quad * 4 + r;
            int d = t * 16 + c;
            ft[(size_t)node * 256 + d * 4 + w] = f2bf(v);
            pel[r] += v * alv[t];
            per[r] += v * arv[t];
        }
    }
#pragma unroll
    for (int r = 0; r < 4; r++) {
#pragma unroll
        for (int mm = 1; mm < 16; mm <<= 1) {
            pel[r] += __shfl_xor(pel[r], mm);
            per[r] += __shfl_xor(per[r], mm);
        }
    }
    if (c == 0) {
#pragma unroll
        for (int r = 0; r < 4; r++) {
            int node = n0 + quad * 4 + r;
            el[node * 4 + w] = pel[r];
            er[node * 4 + w] = per[r];
        }
    }
}

// ---------------- per-dst-node edge softmax + aggregation (wave per node) ----------------
// Plain exp (no max subtraction): logits are O(0.1), softmax is shift-invariant,
// and this removes all per-chunk butterflies + rescaling. Gather loop unrolled x4
// to keep 4 independent L2 loads in flight (round-5 profile: VALUBusy 9% => latency-bound).
__global__ __launch_bounds__(256) void k_agg(
    const u16* __restrict__ ft, const float4* __restrict__ el4, const float4* __restrict__ er4,
    const int* __restrict__ rowptr, const int* __restrict__ csr_src, const float* __restrict__ csr_ew,
    const float* __restrict__ bias, const float* __restrict__ Wg, const float* __restrict__ bg,
    u16* __restrict__ hout, float* __restrict__ gout) {
    int node = blockIdx.x * 4 + (threadIdx.x >> 6);
    int lane = threadIdx.x & 63;
    int beg = rowptr[node], end = rowptr[node + 1];
    float4 erv = er4[node];

    float S0 = 0.f, S1 = 0.f, S2 = 0.f, S3 = 0.f;   // lane-local; reduced once at the end
    float a0 = 0.f, a1 = 0.f, a2 = 0.f, a3 = 0.f;

    for (int base = beg; base < end; base += 64) {
        int cnt = end - base; if (cnt > 64) cnt = 64;
        int sidx = 0;
        float p0 = 0.f, p1 = 0.f, p2 = 0.f, p3 = 0.f;
        if (lane < cnt) {
            sidx = csr_src[base + lane];
            float w = csr_ew[base + lane];
            float4 elv = el4[sidx];
            float t0 = elv.x + erv.x, t1 = elv.y + erv.y, t2 = elv.z + erv.z, t3 = elv.w + erv.w;
            t0 = t0 > 0.f ? t0 : 0.2f * t0;
            t1 = t1 > 0.f ? t1 : 0.2f * t1;
            t2 = t2 > 0.f ? t2 : 0.2f * t2;
            t3 = t3 > 0.f ? t3 : 0.2f * t3;
            p0 = __expf(fminf(t0, 30.f));
            p1 = __expf(fminf(t1, 30.f));
            p2 = __expf(fminf(t2, 30.f));
            p3 = __expf(fminf(t3, 30.f));
            S0 += p0; S1 += p1; S2 += p2; S3 += p3;
            p0 *= w; p1 *= w; p2 *= w; p3 *= w;
        }
        const u16* ftl = ft + lane * 4;
        int k = 0;
        for (; k + 4 <= cnt; k += 4) {
            int sk0 = __shfl(sidx, k), sk1 = __shfl(sidx, k + 1);
            int sk2 = __shfl(sidx, k + 2), sk3 = __shfl(sidx, k + 3);
            uint2 r0 = *(const uint2*)(ftl + (size_t)sk0 * 256);
            uint2 r1 = *(const uint2*)(ftl + (size_t)sk1 * 256);
            uint2 r2 = *(const uint2*)(ftl + (size_t)sk2 * 256);
            uint2 r3 = *(const uint2*)(ftl + (size_t)sk3 * 256);
            float b00 = __shfl(p0, k),     b01 = __shfl(p1, k),     b02 = __shfl(p2, k),     b03 = __shfl(p3, k);
            float b10 = __shfl(p0, k + 1), b11 = __shfl(p1, k + 1), b12 = __shfl(p2, k + 1), b13 = __shfl(p3, k + 1);
            float b20 = __shfl(p0, k + 2), b21 = __shfl(p1, k + 2), b22 = __shfl(p2, k + 2), b23 = __shfl(p3, k + 2);
            float b30 = __shfl(p0, k + 3), b31 = __shfl(p1, k + 3), b32 = __shfl(p2, k + 3), b33 = __shfl(p3, k + 3);
            a0 = fmaf(b00, asfloat(r0.x << 16), a0);
            a1 = fmaf(b01, asfloat(r0.x & 0xffff0000u), a1);
            a2 = fmaf(b02, asfloat(r0.y << 16), a2);
            a3 = fmaf(b03, asfloat(r0.y & 0xffff0000u), a3);
            a0 = fmaf(b10, asfloat(r1.x << 16), a0);
            a1 = fmaf(b11, asfloat(r1.x & 0xffff0000u), a1);
            a2 = fmaf(b12, asfloat(r1.y << 16), a2);
            a3 = fmaf(b13, asfloat(r1.y & 0xffff0000u), a3);
            a0 = fmaf(b20, asfloat(r2.x << 16), a0);
            a1 = fmaf(b21, asfloat(r2.x & 0xffff0000u), a1);
            a2 = fmaf(b22, asfloat(r2.y << 16), a2);
            a3 = fmaf(b23, asfloat(r2.y & 0xffff0000u), a3);
            a0 = fmaf(b30, asfloat(r3.x << 16), a0);
            a1 = fmaf(b31, asfloat(r3.x & 0xffff0000u), a1);
            a2 = fmaf(b32, asfloat(r3.y << 16), a2);
            a3 = fmaf(b33, asfloat(r3.y & 0xffff0000u), a3);
        }
        for (; k < cnt; k++) {
            int sk = __shfl(sidx, k);
            uint2 raw = *(const uint2*)(ftl + (size_t)sk * 256);
            float b0 = __shfl(p0, k), b1 = __shfl(p1, k), b2 = __shfl(p2, k), b3 = __shfl(p3, k);
            a0 = fmaf(b0, asfloat(raw.x << 16), a0);
            a1 = fmaf(b1, asfloat(raw.x & 0xffff0000u), a1);
            a2 = fmaf(b2, asfloat(raw.y << 16), a2);
            a3 = fmaf(b3, asfloat(raw.y & 0xffff0000u), a3);
        }
    }
#pragma unroll
    for (int mm = 1; mm < 64; mm <<= 1) {
        S0 += __shfl_xor(S0, mm);
        S1 += __shfl_xor(S1, mm);
        S2 += __shfl_xor(S2, mm);
        S3 += __shfl_xor(S3, mm);
    }
    float i0 = S0 > 0.f ? 1.f / S0 : 0.f;
    float i1 = S1 > 0.f ? 1.f / S1 : 0.f;
    float i2 = S2 > 0.f ? 1.f / S2 : 0.f;
    float i3 = S3 > 0.f ? 1.f / S3 : 0.f;
    float r0 = a0 * i0 + bias[lane];
    float r1 = a1 * i1 + bias[64 + lane];
    float r2 = a2 * i2 + bias[128 + lane];
    float r3 = a3 * i3 + bias[192 + lane];
    float o = (fmaxf(r0, 0.f) + fmaxf(r1, 0.f) + fmaxf(r2, 0.f) + fmaxf(r3, 0.f)) * 0.25f;
    hout[(size_t)node * 64 + lane] = f2bf(o);
    float pg = o * Wg[lane];
#pragma unroll
    for (int mm = 1; mm < 64; mm <<= 1) pg += __shfl_xor(pg, mm);
    if (lane == 0) gout[node] = pg + bg[0];
}

// ---------------- GlobalAttentionPooling: one block per graph (gid sorted) ----------------
__global__ __launch_bounds__(256) void k_gap(const u16* __restrict__ x, const float* __restrict__ g,
                                             const int* __restrict__ gid, float* __restrict__ hg) {
    int b = blockIdx.x;
    int t = threadIdx.x;
    int lo = 0, hi = N_NODES;
    while (lo < hi) { int mid = (lo + hi) >> 1; if (gid[mid] < b) lo = mid + 1; else hi = mid; }
    int s = lo;
    lo = 0; hi = N_NODES;
    while (lo < hi) { int mid = (lo + hi) >> 1; if (gid[mid] < b + 1) lo = mid + 1; else hi = mid; }
    int e = lo;

    __shared__ float red[256];
    float lm = NEGBIG;
    for (int i = s + t; i < e; i += 256) lm = fmaxf(lm, g[i]);
    red[t] = lm;
    __syncthreads();
    for (int off = 128; off > 0; off >>= 1) {
        if (t < off) red[t] = fmaxf(red[t], red[t + off]);
        __syncthreads();
    }
    float m = red[0];
    __syncthreads();

    int w = t >> 6, lane = t & 63;
    float acc = 0.f, Sp = 0.f;
    for (int i = s + w; i < e; i += 4) {
        float gate = __expf(g[i] - m);
        Sp += gate;
        acc += gate * bf2f(x[(size_t)i * 64 + lane]);
    }
    __shared__ float sacc[4][64];
    __shared__ float ssum[4];
    sacc[w][lane] = acc;
    if (lane == 0) ssum[w] = Sp;
    __syncthreads();
    if (t < 64) {
        float tot = sacc[0][t] + sacc[1][t] + sacc[2][t] + sacc[3][t];
        float S = ssum[0] + ssum[1] + ssum[2] + ssum[3];
        hg[b * 64 + t] = (S > 0.f) ? tot / S : 0.f;
    }
}

// ---------------- LSTM (4 steps) + final linear + sigmoid: one block per batch elem ----------------
__global__ __launch_bounds__(256) void k_lstm(const float* __restrict__ hg,
                                              const float* __restrict__ Wih, const float* __restrict__ Whh,
                                              const float* __restrict__ bih, const float* __restrict__ bhh,
                                              const float* __restrict__ Wc, const float* __restrict__ bc,
                                              float* __restrict__ out) {
    int b = blockIdx.x, t = threadIdx.x;
    __shared__ float h[64], c[64], G[256], xv[64], red[64];
    if (t < 64) { h[t] = 0.f; c[t] = 0.f; }
    __syncthreads();
    for (int step = 0; step < 4; step++) {
        if (t < 64) xv[t] = hg[step * 4096 + b * 64 + t];
        __syncthreads();
        float acc = bih[t] + bhh[t];
#pragma unroll 4
        for (int d = 0; d < 64; d++)
            acc += xv[d] * Wih[t * 64 + d] + h[d] * Whh[t * 64 + d];
        G[t] = acc;
        __syncthreads();
        if (t < 64) {
            float ig = 1.f / (1.f + __expf(-G[t]));
            float fg = 1.f / (1.f + __expf(-G[64 + t]));
            float gg = tanhf(G[128 + t]);
            float og = 1.f / (1.f + __expf(-G[192 + t]));
            float cn = fg * c[t] + ig * gg;
            c[t] = cn;
            h[t] = og * tanhf(cn);
        }
        __syncthreads();
    }
    if (t < 64) red[t] = h[t] * Wc[t];
    __syncthreads();
    if (t == 0) {
        float r = 0.f;
        for (int i = 0; i < 64; i++) r += red[i];
        r += bc[0];
        out[b] = 1.f / (1.f + __expf(-r));
    }
}

extern "C" void kernel_launch(void* const* d_in, const int* in_sizes, int n_in,
                              void* d_out, int out_size, void* d_ws, size_t ws_size,
                              hipStream_t stream) {
    const float* nf   = (const float*)d_in[0];
    const float* nm   = (const float*)d_in[1];
    const float* cent = (const float*)d_in[2];
    const float* ew   = (const float*)d_in[3];
    const int* src  = (const int*)d_in[4];
    const int* dst  = (const int*)d_in[5];
    const int* gid  = (const int*)d_in[6];
    const float* W[3]  = {(const float*)d_in[7],  (const float*)d_in[11], (const float*)d_in[15]};
    const float* al[3] = {(const float*)d_in[8],  (const float*)d_in[12], (const float*)d_in[16]};
    const float* ar[3] = {(const float*)d_in[9],  (const float*)d_in[13], (const float*)d_in[17]};
    const float* bb[3] = {(const float*)d_in[10], (const float*)d_in[14], (const float*)d_in[18]};
    const float* Wg[4] = {(const float*)d_in[19], (const float*)d_in[21], (const float*)d_in[23], (const float*)d_in[25]};
    const float* bg[4] = {(const float*)d_in[20], (const float*)d_in[22], (const float*)d_in[24], (const float*)d_in[26]};
    const float* Wih = (const float*)d_in[27];
    const float* Whh = (const float*)d_in[28];
    const float* bih = (const float*)d_in[29];
    const float* bhh = (const float*)d_in[30];
    const float* Wc  = (const float*)d_in[31];
    const float* bc  = (const float*)d_in[32];
    float* out = (float*)d_out;

    char* p = (char*)d_ws;
    size_t off = 0;
    auto A = [&](size_t bytes) -> char* {
        char* r = p + off;
        off += (bytes + 255) & ~(size_t)255;
        return r;
    };
    u16*   ftb     = (u16*)  A((size_t)N_NODES * 256 * 2);   // 25.6 MB
    u16*   nodebuf = (u16*)  A((size_t)N_NODES * 64 * 2);    // 6.4 MB
    int*   csr_src = (int*)  A((size_t)N_EDGES * 4);         // 3.2 MB
    float* csr_ew  = (float*)A((size_t)N_EDGES * 4);         // 3.2 MB
    float* el      = (float*)A((size_t)N_NODES * 4 * 4);
    float* er      = (float*)A((size_t)N_NODES * 4 * 4);
    float* gbuf    = (float*)A((size_t)N_NODES * 4);
    int*   rowptr  = (int*)  A((size_t)(N_NODES + 1) * 4);
    int*   deg     = (int*)  A((size_t)(N_NODES + 1) * 4);   // becomes scatter cursor
    float* hg      = (float*)A((size_t)4 * 64 * 64 * 4);
    int*   bsum    = (int*)  A((size_t)SCAN_B * 4);
    int*   boff    = (int*)  A((size_t)SCAN_B * 4);
    u16*   Wt      = (u16*)  A((size_t)3 * 64 * 256 * 2);

    hipMemsetAsync(deg, 0, (N_NODES + 1) * sizeof(int), stream);
    k_hist<<<(N_EDGES + 255) / 256, 256, 0, stream>>>(dst, deg);
    k_scanA<<<SCAN_B, 256, 0, stream>>>(deg, rowptr, bsum);
    k_scanB<<<1, 256, 0, stream>>>(bsum, boff);
    k_scanC<<<SCAN_B, 256, 0, stream>>>(boff, rowptr, deg);
    k_scatter<<<(N_EDGES + 255) / 256, 256, 0, stream>>>(src, dst, ew, deg, csr_src, csr_ew);
    k_prep<<<12, 256, 0, stream>>>(W[0], W[1], W[2], Wt);

    k_input<<<N_NODES / 4, 256, 0, stream>>>(nf, nm, cent, Wg[0], bg[0], nodebuf, gbuf);
    k_gap<<<N_GRAPHS, 256, 0, stream>>>(nodebuf, gbuf, gid, hg);

    for (int l = 0; l < 3; l++) {
        k_ft<<<N_NODES / 16, 256, 0, stream>>>(nodebuf, Wt + (size_t)l * 64 * 256, al[l], ar[l], ftb, el, er);
        k_agg<<<N_NODES / 4, 256, 0, stream>>>(ftb, (const float4*)el, (const float4*)er, rowptr,
                                               csr_src, csr_ew, bb[l], Wg[l + 1], bg[l + 1], nodebuf, gbuf);
        k_gap<<<N_GRAPHS, 256, 0, stream>>>(nodebuf, gbuf, gid, hg + (size_t)(l + 1) * 4096);
    }
    k_lstm<<<N_GRAPHS, 256, 0, stream>>>(hg, Wih, Whh, bih, bhh, Wc, bc, out);
}

// Round 7
// 542.443 us; speedup vs baseline: 3.7130x; 1.3820x over previous
//
#include <hip/hip_runtime.h>
#include <hip/hip_bf16.h>

#define N_NODES 50000
#define N_EDGES 800000
#define N_GRAPHS 64
#define SCAN_B 196   // ceil(N_NODES/256)

typedef unsigned short u16;
typedef short s16x8 __attribute__((ext_vector_type(8)));
typedef float f32x4 __attribute__((ext_vector_type(4)));

#define NEGBIG -3.0e38f

__device__ __forceinline__ float bf2f(u16 u) {
    union { unsigned int i; float f; } v; v.i = ((unsigned int)u) << 16; return v.f;
}
__device__ __forceinline__ u16 f2bf(float f) {
    union { float f; unsigned int i; } v; v.f = f;
    unsigned int i = v.i;
    unsigned int r = i + 0x7fffu + ((i >> 16) & 1u);
    return (u16)(r >> 16);
}
__device__ __forceinline__ float asfloat(unsigned int u) {
    union { unsigned int i; float f; } v; v.i = u; return v.f;
}

// ---------------- CSR build (by dst) ----------------
__global__ __launch_bounds__(256) void k_hist(const int* __restrict__ dst, int* __restrict__ deg) {
    int e = blockIdx.x * 256 + threadIdx.x;
    if (e < N_EDGES) atomicAdd(&deg[dst[e]], 1);
}

__global__ __launch_bounds__(256) void k_scanA(const int* __restrict__ deg,
                                               int* __restrict__ rowptr, int* __restrict__ bsum) {
    int b = blockIdx.x, t = threadIdx.x;
    int i = b * 256 + t;
    int v = (i < N_NODES) ? deg[i] : 0;
    int orig = v;
    int lane = t & 63, w = t >> 6;
#pragma unroll
    for (int d = 1; d < 64; d <<= 1) {
        int u = __shfl_up(v, d);
        if (lane >= d) v += u;
    }
    __shared__ int wsum[4];
    if (lane == 63) wsum[w] = v;
    __syncthreads();
    int add = 0;
    for (int k = 0; k < w; k++) add += wsum[k];
    v += add;
    if (i < N_NODES) rowptr[i] = v - orig;
    if (t == 255) bsum[b] = v;
}

__global__ __launch_bounds__(256) void k_scanB(const int* __restrict__ bsum, int* __restrict__ boff) {
    int t = threadIdx.x;
    int v = (t < SCAN_B) ? bsum[t] : 0;
    int orig = v;
    int lane = t & 63, w = t >> 6;
#pragma unroll
    for (int d = 1; d < 64; d <<= 1) {
        int u = __shfl_up(v, d);
        if (lane >= d) v += u;
    }
    __shared__ int wsum[4];
    if (lane == 63) wsum[w] = v;
    __syncthreads();
    int add = 0;
    for (int k = 0; k < w; k++) add += wsum[k];
    v += add;
    if (t < SCAN_B) boff[t] = v - orig;
}

__global__ __launch_bounds__(256) void k_scanC(const int* __restrict__ boff,
                                               int* __restrict__ rowptr, int* __restrict__ deg) {
    int b = blockIdx.x, t = threadIdx.x;
    int i = b * 256 + t;
    if (i < N_NODES) {
        int val = rowptr[i] + boff[b];
        int d = deg[i];
        rowptr[i] = val;
        deg[i] = val;
        if (i == N_NODES - 1) rowptr[N_NODES] = val + d;
    }
}

__global__ __launch_bounds__(256) void k_scatter(const int* __restrict__ src, const int* __restrict__ dst,
                                                 const float* __restrict__ ew, int* __restrict__ cursor,
                                                 int* __restrict__ csr_src, float* __restrict__ csr_ew) {
    int e = blockIdx.x * 256 + threadIdx.x;
    if (e < N_EDGES) {
        int d = dst[e];
        int pos = atomicAdd(&cursor[d], 1);
        csr_src[pos] = src[e];
        csr_ew[pos] = ew[e];
    }
}

// ---------------- W (f32, [64][256]) -> Wt (bf16, [256 col][64 d]), LDS tile transpose ----------------
__global__ __launch_bounds__(256) void k_prep(const float* __restrict__ W1, const float* __restrict__ W2,
                                              const float* __restrict__ W3, u16* __restrict__ Wt) {
    int l = blockIdx.x >> 2, ti = blockIdx.x & 3;
    const float* W = (l == 0) ? W1 : (l == 1) ? W2 : W3;
    u16* o = Wt + (size_t)l * 64 * 256;
    __shared__ float tile[64][65];
    int t = threadIdx.x;
    for (int i = t; i < 64 * 64; i += 256) {
        int d = i >> 6, c = i & 63;
        tile[d][c] = W[d * 256 + ti * 64 + c];
    }
    __syncthreads();
    for (int i = t; i < 64 * 64; i += 256) {
        int c = i >> 6, d = i & 63;
        o[(size_t)(ti * 64 + c) * 64 + d] = f2bf(tile[d][c]);
    }
}

// ---------------- x = concat(nfeats,names)*centrality, fused gap0 gate logit ----------------
__global__ __launch_bounds__(256) void k_input(const float* __restrict__ nf, const float* __restrict__ nm,
                                               const float* __restrict__ cent, const float* __restrict__ Wg,
                                               const float* __restrict__ bg,
                                               u16* __restrict__ x, float* __restrict__ g) {
    int node = blockIdx.x * 4 + (threadIdx.x >> 6);
    int lane = threadIdx.x & 63;
    float v = (lane < 48) ? nf[(size_t)node * 48 + lane] : nm[(size_t)node * 16 + lane - 48];
    float xf = v * cent[node];
    x[(size_t)node * 64 + lane] = f2bf(xf);
    float p = xf * Wg[lane];
#pragma unroll
    for (int mm = 1; mm < 64; mm <<= 1) p += __shfl_xor(p, mm);
    if (lane == 0) g[node] = p + bg[0];
}

// ---------------- ft = X @ W via MFMA 16x16x32 bf16, epilogue computes el/er ----------------
__global__ __launch_bounds__(256) void k_ft(const u16* __restrict__ X, const u16* __restrict__ Wt,
                                            const float* __restrict__ al, const float* __restrict__ ar,
                                            u16* __restrict__ ft, float* __restrict__ el, float* __restrict__ er) {
    int w = threadIdx.x >> 6;
    int lane = threadIdx.x & 63;
    int quad = lane >> 4, c = lane & 15;
    int n0 = blockIdx.x * 16;

    f32x4 acc[4];
#pragma unroll
    for (int t = 0; t < 4; t++) acc[t] = (f32x4){0.f, 0.f, 0.f, 0.f};

#pragma unroll
    for (int kh = 0; kh < 2; kh++) {
        s16x8 a = *(const s16x8*)(X + (size_t)(n0 + c) * 64 + kh * 32 + quad * 8);
#pragma unroll
        for (int t = 0; t < 4; t++) {
            int col = w * 64 + t * 16 + c;
            s16x8 b = *(const s16x8*)(Wt + (size_t)col * 64 + kh * 32 + quad * 8);
            acc[t] = __builtin_amdgcn_mfma_f32_16x16x32_bf16(a, b, acc[t], 0, 0, 0);
        }
    }

    float alv[4], arv[4];
#pragma unroll
    for (int t = 0; t < 4; t++) {
        alv[t] = al[w * 64 + t * 16 + c];
        arv[t] = ar[w * 64 + t * 16 + c];
    }
    float pel[4] = {0.f, 0.f, 0.f, 0.f}, per[4] = {0.f, 0.f, 0.f, 0.f};
#pragma unroll
    for (int t = 0; t < 4; t++) {
#pragma unroll
        for (int r = 0; r < 4; r++) {
            float v = acc[t][r];
            int node = n0 + quad * 4 + r;
            int d = t * 16 + c;
            ft[(size_t)node * 256 + d * 4 + w] = f2bf(v);
            pel[r] += v * alv[t];
            per[r] += v * arv[t];
        }
    }
#pragma unroll
    for (int r = 0; r < 4; r++) {
#pragma unroll
        for (int mm = 1; mm < 16; mm <<= 1) {
            pel[r] += __shfl_xor(pel[r], mm);
            per[r] += __shfl_xor(per[r], mm);
        }
    }
    if (c == 0) {
#pragma unroll
        for (int r = 0; r < 4; r++) {
            int node = n0 + quad * 4 + r;
            el[node * 4 + w] = pel[r];
            er[node * 4 + w] = per[r];
        }
    }
}

// ---------------- per-dst-node edge softmax + aggregation (wave per node) ----------------
// Per-edge p/src broadcast via wave-local LDS (same-address reads are free) instead of 5 shfl.
__global__ __launch_bounds__(256) void k_agg(
    const u16* __restrict__ ft, const float4* __restrict__ el4, const float4* __restrict__ er4,
    const int* __restrict__ rowptr, const int* __restrict__ csr_src, const float* __restrict__ csr_ew,
    const float* __restrict__ bias, const float* __restrict__ Wg, const float* __restrict__ bg,
    u16* __restrict__ hout, float* __restrict__ gout) {
    int wv = threadIdx.x >> 6;
    int node = blockIdx.x * 4 + wv;
    int lane = threadIdx.x & 63;
    int beg = rowptr[node], end = rowptr[node + 1];
    float4 erv = er4[node];

    __shared__ int    s_off[4][64];
    __shared__ float4 s_p[4][64];

    float S0 = 0.f, S1 = 0.f, S2 = 0.f, S3 = 0.f;
    float a0 = 0.f, a1 = 0.f, a2 = 0.f, a3 = 0.f;

    const char* ftl = (const char*)ft + lane * 8;

    for (int base = beg; base < end; base += 64) {
        int cnt = end - base; if (cnt > 64) cnt = 64;
        if (lane < cnt) {
            int sidx = csr_src[base + lane];
            float w = csr_ew[base + lane];
            float4 elv = el4[sidx];
            float t0 = elv.x + erv.x, t1 = elv.y + erv.y, t2 = elv.z + erv.z, t3 = elv.w + erv.w;
            t0 = t0 > 0.f ? t0 : 0.2f * t0;
            t1 = t1 > 0.f ? t1 : 0.2f * t1;
            t2 = t2 > 0.f ? t2 : 0.2f * t2;
            t3 = t3 > 0.f ? t3 : 0.2f * t3;
            float p0 = __expf(fminf(t0, 30.f));
            float p1 = __expf(fminf(t1, 30.f));
            float p2 = __expf(fminf(t2, 30.f));
            float p3 = __expf(fminf(t3, 30.f));
            S0 += p0; S1 += p1; S2 += p2; S3 += p3;
            s_off[wv][lane] = sidx * 512;   // byte offset into ft
            s_p[wv][lane] = make_float4(p0 * w, p1 * w, p2 * w, p3 * w);
        }
        int k = 0;
        for (; k + 4 <= cnt; k += 4) {
            int o0 = s_off[wv][k], o1 = s_off[wv][k + 1], o2 = s_off[wv][k + 2], o3 = s_off[wv][k + 3];
            uint2 r0 = *(const uint2*)(ftl + o0);
            uint2 r1 = *(const uint2*)(ftl + o1);
            uint2 r2 = *(const uint2*)(ftl + o2);
            uint2 r3 = *(const uint2*)(ftl + o3);
            float4 q0 = s_p[wv][k], q1 = s_p[wv][k + 1], q2 = s_p[wv][k + 2], q3 = s_p[wv][k + 3];
            a0 = fmaf(q0.x, asfloat(r0.x << 16), a0);
            a1 = fmaf(q0.y, asfloat(r0.x & 0xffff0000u), a1);
            a2 = fmaf(q0.z, asfloat(r0.y << 16), a2);
            a3 = fmaf(q0.w, asfloat(r0.y & 0xffff0000u), a3);
            a0 = fmaf(q1.x, asfloat(r1.x << 16), a0);
            a1 = fmaf(q1.y, asfloat(r1.x & 0xffff0000u), a1);
            a2 = fmaf(q1.z, asfloat(r1.y << 16), a2);
            a3 = fmaf(q1.w, asfloat(r1.y & 0xffff0000u), a3);
            a0 = fmaf(q2.x, asfloat(r2.x << 16), a0);
            a1 = fmaf(q2.y, asfloat(r2.x & 0xffff0000u), a1);
            a2 = fmaf(q2.z, asfloat(r2.y << 16), a2);
            a3 = fmaf(q2.w, asfloat(r2.y & 0xffff0000u), a3);
            a0 = fmaf(q3.x, asfloat(r3.x << 16), a0);
            a1 = fmaf(q3.y, asfloat(r3.x & 0xffff0000u), a1);
            a2 = fmaf(q3.z, asfloat(r3.y << 16), a2);
            a3 = fmaf(q3.w, asfloat(r3.y & 0xffff0000u), a3);
        }
        for (; k < cnt; k++) {
            int o0 = s_off[wv][k];
            float4 q0 = s_p[wv][k];
            uint2 r0 = *(const uint2*)(ftl + o0);
            a0 = fmaf(q0.x, asfloat(r0.x << 16), a0);
            a1 = fmaf(q0.y, asfloat(r0.x & 0xffff0000u), a1);
            a2 = fmaf(q0.z, asfloat(r0.y << 16), a2);
            a3 = fmaf(q0.w, asfloat(r0.y & 0xffff0000u), a3);
        }
    }
#pragma unroll
    for (int mm = 1; mm < 64; mm <<= 1) {
        S0 += __shfl_xor(S0, mm);
        S1 += __shfl_xor(S1, mm);
        S2 += __shfl_xor(S2, mm);
        S3 += __shfl_xor(S3, mm);
    }
    float i0 = S0 > 0.f ? 1.f / S0 : 0.f;
    float i1 = S1 > 0.f ? 1.f / S1 : 0.f;
    float i2 = S2 > 0.f ? 1.f / S2 : 0.f;
    float i3 = S3 > 0.f ? 1.f / S3 : 0.f;
    float r0 = a0 * i0 + bias[lane];
    float r1 = a1 * i1 + bias[64 + lane];
    float r2 = a2 * i2 + bias[128 + lane];
    float r3 = a3 * i3 + bias[192 + lane];
    float o = (fmaxf(r0, 0.f) + fmaxf(r1, 0.f) + fmaxf(r2, 0.f) + fmaxf(r3, 0.f)) * 0.25f;
    hout[(size_t)node * 64 + lane] = f2bf(o);
    float pg = o * Wg[lane];
#pragma unroll
    for (int mm = 1; mm < 64; mm <<= 1) pg += __shfl_xor(pg, mm);
    if (lane == 0) gout[node] = pg + bg[0];
}

// ---------------- GAP phase-1: 8 parts per graph, no-max exp, vectorized ----------------
// grid = 64 graphs * 8 parts. pnum[b][part][64], pden[b][part].
__global__ __launch_bounds__(256) void k_gapP(const u16* __restrict__ x, const float* __restrict__ g,
                                              const int* __restrict__ gid,
                                              float* __restrict__ pnum, float* __restrict__ pden) {
    int part = blockIdx.x & 7, b = blockIdx.x >> 3;
    int t = threadIdx.x, w = t >> 6, lane = t & 63, q = lane >> 4, c = lane & 15;
    int lo = 0, hi = N_NODES;
    while (lo < hi) { int mid = (lo + hi) >> 1; if (gid[mid] < b) lo = mid + 1; else hi = mid; }
    int s = lo;
    lo = 0; hi = N_NODES;
    while (lo < hi) { int mid = (lo + hi) >> 1; if (gid[mid] < b + 1) lo = mid + 1; else hi = mid; }
    int e = lo;
    int len = e - s;
    int ps = s + (int)(((long long)len * part) >> 3);
    int pe = s + (int)(((long long)len * (part + 1)) >> 3);

    float a0 = 0.f, a1 = 0.f, a2 = 0.f, a3 = 0.f, den = 0.f;
    // each wave: 4 nodes/iter (lane group q -> node, c -> 4 dims)
    for (int n0 = ps + w * 4; n0 < pe; n0 += 16) {
        int node = n0 + q;
        if (node < pe) {
            float gate = __expf(fminf(g[node], 30.f));
            uint2 raw = *(const uint2*)(x + (size_t)node * 64 + c * 4);
            a0 = fmaf(gate, asfloat(raw.x << 16), a0);
            a1 = fmaf(gate, asfloat(raw.x & 0xffff0000u), a1);
            a2 = fmaf(gate, asfloat(raw.y << 16), a2);
            a3 = fmaf(gate, asfloat(raw.y & 0xffff0000u), a3);
            if (c == 0) den += gate;
        }
    }
#pragma unroll
    for (int mm = 16; mm < 64; mm <<= 1) {
        a0 += __shfl_xor(a0, mm); a1 += __shfl_xor(a1, mm);
        a2 += __shfl_xor(a2, mm); a3 += __shfl_xor(a3, mm);
        den += __shfl_xor(den, mm);
    }
    __shared__ float snum[4][64];
    __shared__ float sden[4];
    if (lane < 16) {
        snum[w][c * 4 + 0] = a0; snum[w][c * 4 + 1] = a1;
        snum[w][c * 4 + 2] = a2; snum[w][c * 4 + 3] = a3;
        if (lane == 0) sden[w] = den;
    }
    __syncthreads();
    if (t < 64) pnum[((size_t)b * 8 + part) * 64 + t] = snum[0][t] + snum[1][t] + snum[2][t] + snum[3][t];
    if (t == 0) pden[b * 8 + part] = sden[0] + sden[1] + sden[2] + sden[3];
}

// ---------------- LSTM (4 steps) + final linear + sigmoid; combines gap partials ----------------
__global__ __launch_bounds__(256) void k_lstm(const float* __restrict__ pnum, const float* __restrict__ pden,
                                              const float* __restrict__ Wih, const float* __restrict__ Whh,
                                              const float* __restrict__ bih, const float* __restrict__ bhh,
                                              const float* __restrict__ Wc, const float* __restrict__ bc,
                                              float* __restrict__ out) {
    int b = blockIdx.x, t = threadIdx.x;
    __shared__ float h[64], c[64], G[256], xv[64], red[64];
    if (t < 64) { h[t] = 0.f; c[t] = 0.f; }
    __syncthreads();
    for (int step = 0; step < 4; step++) {
        if (t < 64) {
            const float* pn = pnum + (((size_t)step * N_GRAPHS + b) * 8) * 64;
            const float* pd = pden + ((size_t)step * N_GRAPHS + b) * 8;
            float num = 0.f, dn = 0.f;
#pragma unroll
            for (int pp = 0; pp < 8; pp++) { num += pn[pp * 64 + t]; dn += pd[pp]; }
            xv[t] = (dn > 0.f) ? num / dn : 0.f;
        }
        __syncthreads();
        float acc = bih[t] + bhh[t];
#pragma unroll 4
        for (int d = 0; d < 64; d++)
            acc += xv[d] * Wih[t * 64 + d] + h[d] * Whh[t * 64 + d];
        G[t] = acc;
        __syncthreads();
        if (t < 64) {
            float ig = 1.f / (1.f + __expf(-G[t]));
            float fg = 1.f / (1.f + __expf(-G[64 + t]));
            float gg = tanhf(G[128 + t]);
            float og = 1.f / (1.f + __expf(-G[192 + t]));
            float cn = fg * c[t] + ig * gg;
            c[t] = cn;
            h[t] = og * tanhf(cn);
        }
        __syncthreads();
    }
    if (t < 64) red[t] = h[t] * Wc[t];
    __syncthreads();
    if (t == 0) {
        float r = 0.f;
        for (int i = 0; i < 64; i++) r += red[i];
        r += bc[0];
        out[b] = 1.f / (1.f + __expf(-r));
    }
}

extern "C" void kernel_launch(void* const* d_in, const int* in_sizes, int n_in,
                              void* d_out, int out_size, void* d_ws, size_t ws_size,
                              hipStream_t stream) {
    const float* nf   = (const float*)d_in[0];
    const float* nm   = (const float*)d_in[1];
    const float* cent = (const float*)d_in[2];
    const float* ew   = (const float*)d_in[3];
    const int* src  = (const int*)d_in[4];
    const int* dst  = (const int*)d_in[5];
    const int* gid  = (const int*)d_in[6];
    const float* W[3]  = {(const float*)d_in[7],  (const float*)d_in[11], (const float*)d_in[15]};
    const float* al[3] = {(const float*)d_in[8],  (const float*)d_in[12], (const float*)d_in[16]};
    const float* ar[3] = {(const float*)d_in[9],  (const float*)d_in[13], (const float*)d_in[17]};
    const float* bb[3] = {(const float*)d_in[10], (const float*)d_in[14], (const float*)d_in[18]};
    const float* Wg[4] = {(const float*)d_in[19], (const float*)d_in[21], (const float*)d_in[23], (const float*)d_in[25]};
    const float* bg[4] = {(const float*)d_in[20], (const float*)d_in[22], (const float*)d_in[24], (const float*)d_in[26]};
    const float* Wih = (const float*)d_in[27];
    const float* Whh = (const float*)d_in[28];
    const float* bih = (const float*)d_in[29];
    const float* bhh = (const float*)d_in[30];
    const float* Wc  = (const float*)d_in[31];
    const float* bc  = (const float*)d_in[32];
    float* out = (float*)d_out;

    char* p = (char*)d_ws;
    size_t off = 0;
    auto A = [&](size_t bytes) -> char* {
        char* r = p + off;
        off += (bytes + 255) & ~(size_t)255;
        return r;
    };
    u16*   ftb     = (u16*)  A((size_t)N_NODES * 256 * 2);   // 25.6 MB
    u16*   nodebuf = (u16*)  A((size_t)N_NODES * 64 * 2);    // 6.4 MB
    int*   csr_src = (int*)  A((size_t)N_EDGES * 4);         // 3.2 MB
    float* csr_ew  = (float*)A((size_t)N_EDGES * 4);         // 3.2 MB
    float* el      = (float*)A((size_t)N_NODES * 4 * 4);
    float* er      = (float*)A((size_t)N_NODES * 4 * 4);
    float* gbuf    = (float*)A((size_t)N_NODES * 4);
    int*   rowptr  = (int*)  A((size_t)(N_NODES + 1) * 4);
    int*   deg     = (int*)  A((size_t)(N_NODES + 1) * 4);   // becomes scatter cursor
    float* pnum    = (float*)A((size_t)4 * N_GRAPHS * 8 * 64 * 4);  // 512 KB
    float* pden    = (float*)A((size_t)4 * N_GRAPHS * 8 * 4);
    int*   bsum    = (int*)  A((size_t)SCAN_B * 4);
    int*   boff    = (int*)  A((size_t)SCAN_B * 4);
    u16*   Wt      = (u16*)  A((size_t)3 * 64 * 256 * 2);

    hipMemsetAsync(deg, 0, (N_NODES + 1) * sizeof(int), stream);
    k_hist<<<(N_EDGES + 255) / 256, 256, 0, stream>>>(dst, deg);
    k_scanA<<<SCAN_B, 256, 0, stream>>>(deg, rowptr, bsum);
    k_scanB<<<1, 256, 0, stream>>>(bsum, boff);
    k_scanC<<<SCAN_B, 256, 0, stream>>>(boff, rowptr, deg);
    k_scatter<<<(N_EDGES + 255) / 256, 256, 0, stream>>>(src, dst, ew, deg, csr_src, csr_ew);
    k_prep<<<12, 256, 0, stream>>>(W[0], W[1], W[2], Wt);

    k_input<<<N_NODES / 4, 256, 0, stream>>>(nf, nm, cent, Wg[0], bg[0], nodebuf, gbuf);
    k_gapP<<<N_GRAPHS * 8, 256, 0, stream>>>(nodebuf, gbuf, gid, pnum, pden);

    for (int l = 0; l < 3; l++) {
        k_ft<<<N_NODES / 16, 256, 0, stream>>>(nodebuf, Wt + (size_t)l * 64 * 256, al[l], ar[l], ftb, el, er);
        k_agg<<<N_NODES / 4, 256, 0, stream>>>(ftb, (const float4*)el, (const float4*)er, rowptr,
                                               csr_src, csr_ew, bb[l], Wg[l + 1], bg[l + 1], nodebuf, gbuf);
        k_gapP<<<N_GRAPHS * 8, 256, 0, stream>>>(nodebuf, gbuf, gid,
                                                 pnum + (size_t)(l + 1) * N_GRAPHS * 8 * 64,
                                                 pden + (size_t)(l + 1) * N_GRAPHS * 8);
    }
    k_lstm<<<N_GRAPHS, 256, 0, stream>>>(pnum, pden, Wih, Whh, bih, bhh, Wc, bc, out);
}

// Round 8
// 496.906 us; speedup vs baseline: 4.0533x; 1.0916x over previous
//
#include <hip/hip_runtime.h>
#include <hip/hip_bf16.h>

#define N_NODES 50000
#define N_EDGES 800000
#define N_GRAPHS 64
#define SCAN_B 196   // ceil(N_NODES/256)
#define FT_B   3125  // N_NODES/16
#define GAP_B  512   // 64 graphs * 8 parts

typedef unsigned short u16;
typedef short s16x8 __attribute__((ext_vector_type(8)));
typedef float f32x4 __attribute__((ext_vector_type(4)));

__device__ __forceinline__ float bf2f(u16 u) {
    union { unsigned int i; float f; } v; v.i = ((unsigned int)u) << 16; return v.f;
}
__device__ __forceinline__ u16 f2bf(float f) {
    union { float f; unsigned int i; } v; v.f = f;
    unsigned int i = v.i;
    unsigned int r = i + 0x7fffu + ((i >> 16) & 1u);
    return (u16)(r >> 16);
}
__device__ __forceinline__ float asfloat(unsigned int u) {
    union { unsigned int i; float f; } v; v.i = u; return v.f;
}

// ---------------- fused: zero deg + (x = concat*centrality, gate logit) ----------------
__global__ __launch_bounds__(256) void k_init(const float* __restrict__ nf, const float* __restrict__ nm,
                                              const float* __restrict__ cent, const float* __restrict__ Wg,
                                              const float* __restrict__ bg,
                                              u16* __restrict__ x, float* __restrict__ g,
                                              int* __restrict__ deg) {
    int b = blockIdx.x;
    if (b < SCAN_B) {                 // zero deg[0..N_NODES]
        int i = b * 256 + threadIdx.x;
        if (i <= N_NODES) deg[i] = 0;
        return;
    }
    b -= SCAN_B;
    int node = b * 4 + (threadIdx.x >> 6);
    int lane = threadIdx.x & 63;
    float v = (lane < 48) ? nf[(size_t)node * 48 + lane] : nm[(size_t)node * 16 + lane - 48];
    float xf = v * cent[node];
    x[(size_t)node * 64 + lane] = f2bf(xf);
    float p = xf * Wg[lane];
#pragma unroll
    for (int mm = 1; mm < 64; mm <<= 1) p += __shfl_xor(p, mm);
    if (lane == 0) g[node] = p + bg[0];
}

// ---------------- CSR build (by dst) ----------------
__global__ __launch_bounds__(256) void k_hist(const int* __restrict__ dst, int* __restrict__ deg) {
    int e = blockIdx.x * 256 + threadIdx.x;
    if (e < N_EDGES) atomicAdd(&deg[dst[e]], 1);
}

__global__ __launch_bounds__(256) void k_scanA(const int* __restrict__ deg,
                                               int* __restrict__ rowptr, int* __restrict__ bsum) {
    int b = blockIdx.x, t = threadIdx.x;
    int i = b * 256 + t;
    int v = (i < N_NODES) ? deg[i] : 0;
    int orig = v;
    int lane = t & 63, w = t >> 6;
#pragma unroll
    for (int d = 1; d < 64; d <<= 1) {
        int u = __shfl_up(v, d);
        if (lane >= d) v += u;
    }
    __shared__ int wsum[4];
    if (lane == 63) wsum[w] = v;
    __syncthreads();
    int add = 0;
    for (int k = 0; k < w; k++) add += wsum[k];
    v += add;
    if (i < N_NODES) rowptr[i] = v - orig;
    if (t == 255) bsum[b] = v;
}

// fused: block 0 = scan of block sums; blocks 1..12 = W transpose (independent)
__global__ __launch_bounds__(256) void k_scanBprep(const int* __restrict__ bsum, int* __restrict__ boff,
                                                   const float* __restrict__ W1, const float* __restrict__ W2,
                                                   const float* __restrict__ W3, u16* __restrict__ Wt) {
    __shared__ float tile[64][65];
    __shared__ int wsum[4];
    if (blockIdx.x == 0) {
        int t = threadIdx.x;
        int v = (t < SCAN_B) ? bsum[t] : 0;
        int orig = v;
        int lane = t & 63, w = t >> 6;
#pragma unroll
        for (int d = 1; d < 64; d <<= 1) {
            int u = __shfl_up(v, d);
            if (lane >= d) v += u;
        }
        if (lane == 63) wsum[w] = v;
        __syncthreads();
        int add = 0;
        for (int k = 0; k < w; k++) add += wsum[k];
        v += add;
        if (t < SCAN_B) boff[t] = v - orig;
        return;
    }
    int bb = blockIdx.x - 1;
    int l = bb >> 2, ti = bb & 3;
    const float* W = (l == 0) ? W1 : (l == 1) ? W2 : W3;
    u16* o = Wt + (size_t)l * 64 * 256;
    int t = threadIdx.x;
    for (int i = t; i < 64 * 64; i += 256) {
        int d = i >> 6, c = i & 63;
        tile[d][c] = W[d * 256 + ti * 64 + c];
    }
    __syncthreads();
    for (int i = t; i < 64 * 64; i += 256) {
        int c = i >> 6, d = i & 63;
        o[(size_t)(ti * 64 + c) * 64 + d] = f2bf(tile[d][c]);
    }
}

__global__ __launch_bounds__(256) void k_scanC(const int* __restrict__ boff,
                                               int* __restrict__ rowptr, int* __restrict__ deg) {
    int b = blockIdx.x, t = threadIdx.x;
    int i = b * 256 + t;
    if (i < N_NODES) {
        int val = rowptr[i] + boff[b];
        int d = deg[i];
        rowptr[i] = val;
        deg[i] = val;
        if (i == N_NODES - 1) rowptr[N_NODES] = val + d;
    }
}

// packed (src, ew) scatter: ONE 8B random write per edge (halves line touches)
__global__ __launch_bounds__(256) void k_scatter(const int* __restrict__ src, const int* __restrict__ dst,
                                                 const float* __restrict__ ew, int* __restrict__ cursor,
                                                 int2* __restrict__ csr_se) {
    int e = blockIdx.x * 256 + threadIdx.x;
    if (e < N_EDGES) {
        int d = dst[e];
        int pos = atomicAdd(&cursor[d], 1);
        csr_se[pos] = make_int2(src[e], __float_as_int(ew[e]));
    }
}

// ---------------- GAP partial (device fn): 8 parts/graph, no-max exp ----------------
__device__ __forceinline__ void gap_part(int pb, const u16* __restrict__ x, const float* __restrict__ g,
                                         const int* __restrict__ gid,
                                         float* __restrict__ pnum, float* __restrict__ pden) {
    int part = pb & 7, b = pb >> 3;
    int t = threadIdx.x, w = t >> 6, lane = t & 63, q = lane >> 4, c = lane & 15;
    int lo = 0, hi = N_NODES;
    while (lo < hi) { int mid = (lo + hi) >> 1; if (gid[mid] < b) lo = mid + 1; else hi = mid; }
    int s = lo;
    lo = 0; hi = N_NODES;
    while (lo < hi) { int mid = (lo + hi) >> 1; if (gid[mid] < b + 1) lo = mid + 1; else hi = mid; }
    int e = lo;
    int len = e - s;
    int ps = s + (int)(((long long)len * part) >> 3);
    int pe = s + (int)(((long long)len * (part + 1)) >> 3);

    float a0 = 0.f, a1 = 0.f, a2 = 0.f, a3 = 0.f, den = 0.f;
    for (int n0 = ps + w * 4; n0 < pe; n0 += 16) {
        int node = n0 + q;
        if (node < pe) {
            float gate = __expf(fminf(g[node], 30.f));
            uint2 raw = *(const uint2*)(x + (size_t)node * 64 + c * 4);
            a0 = fmaf(gate, asfloat(raw.x << 16), a0);
            a1 = fmaf(gate, asfloat(raw.x & 0xffff0000u), a1);
            a2 = fmaf(gate, asfloat(raw.y << 16), a2);
            a3 = fmaf(gate, asfloat(raw.y & 0xffff0000u), a3);
            if (c == 0) den += gate;
        }
    }
#pragma unroll
    for (int mm = 16; mm < 64; mm <<= 1) {
        a0 += __shfl_xor(a0, mm); a1 += __shfl_xor(a1, mm);
        a2 += __shfl_xor(a2, mm); a3 += __shfl_xor(a3, mm);
        den += __shfl_xor(den, mm);
    }
    __shared__ float snum[4][64];
    __shared__ float sden[4];
    if (lane < 16) {
        snum[w][c * 4 + 0] = a0; snum[w][c * 4 + 1] = a1;
        snum[w][c * 4 + 2] = a2; snum[w][c * 4 + 3] = a3;
        if (lane == 0) sden[w] = den;
    }
    __syncthreads();
    if (t < 64) pnum[((size_t)b * 8 + part) * 64 + t] = snum[0][t] + snum[1][t] + snum[2][t] + snum[3][t];
    if (t == 0) pden[b * 8 + part] = sden[0] + sden[1] + sden[2] + sden[3];
}

// ---------------- fused: ft = X @ W (MFMA) + el/er  |  GAP partials for previous state ----------------
// blocks 0..FT_B-1: ft; blocks FT_B..FT_B+GAP_B-1: gap.
__global__ __launch_bounds__(256) void k_ftgap(const u16* __restrict__ X, const u16* __restrict__ Wt,
                                               const float* __restrict__ al, const float* __restrict__ ar,
                                               u16* __restrict__ ft, float* __restrict__ el, float* __restrict__ er,
                                               const float* __restrict__ g, const int* __restrict__ gid,
                                               float* __restrict__ pnum, float* __restrict__ pden) {
    if (blockIdx.x >= FT_B) {
        gap_part(blockIdx.x - FT_B, X, g, gid, pnum, pden);
        return;
    }
    int w = threadIdx.x >> 6;
    int lane = threadIdx.x & 63;
    int quad = lane >> 4, c = lane & 15;
    int n0 = blockIdx.x * 16;

    f32x4 acc[4];
#pragma unroll
    for (int t = 0; t < 4; t++) acc[t] = (f32x4){0.f, 0.f, 0.f, 0.f};

#pragma unroll
    for (int kh = 0; kh < 2; kh++) {
        s16x8 a = *(const s16x8*)(X + (size_t)(n0 + c) * 64 + kh * 32 + quad * 8);
#pragma unroll
        for (int t = 0; t < 4; t++) {
            int col = w * 64 + t * 16 + c;
            s16x8 b = *(const s16x8*)(Wt + (size_t)col * 64 + kh * 32 + quad * 8);
            acc[t] = __builtin_amdgcn_mfma_f32_16x16x32_bf16(a, b, acc[t], 0, 0, 0);
        }
    }

    // stage bf16 tile in LDS, then coalesced dwordx4 stores (fixes 2B-scatter writes)
    __shared__ u16 sft[16 * 256];
    float alv[4], arv[4];
#pragma unroll
    for (int t = 0; t < 4; t++) {
        alv[t] = al[w * 64 + t * 16 + c];
        arv[t] = ar[w * 64 + t * 16 + c];
    }
    float pel[4] = {0.f, 0.f, 0.f, 0.f}, per[4] = {0.f, 0.f, 0.f, 0.f};
#pragma unroll
    for (int t = 0; t < 4; t++) {
#pragma unroll
        for (int r = 0; r < 4; r++) {
            float v = acc[t][r];
            int nl = quad * 4 + r;
            int d = t * 16 + c;
            sft[nl * 256 + d * 4 + w] = f2bf(v);
            pel[r] += v * alv[t];
            per[r] += v * arv[t];
        }
    }
#pragma unroll
    for (int r = 0; r < 4; r++) {
#pragma unroll
        for (int mm = 1; mm < 16; mm <<= 1) {
            pel[r] += __shfl_xor(pel[r], mm);
            per[r] += __shfl_xor(per[r], mm);
        }
    }
    if (c == 0) {
#pragma unroll
        for (int r = 0; r < 4; r++) {
            int node = n0 + quad * 4 + r;
            el[node * 4 + w] = pel[r];
            er[node * 4 + w] = per[r];
        }
    }
    __syncthreads();
    const uint4* s4 = (const uint4*)sft;
    uint4* g4 = (uint4*)(ft + (size_t)n0 * 256);
#pragma unroll
    for (int i = 0; i < 2; i++) g4[i * 256 + threadIdx.x] = s4[i * 256 + threadIdx.x];
}

// ---------------- per-dst-node edge softmax + aggregation (wave per node) ----------------
__global__ __launch_bounds__(256) void k_agg(
    const u16* __restrict__ ft, const float4* __restrict__ el4, const float4* __restrict__ er4,
    const int* __restrict__ rowptr, const int2* __restrict__ csr_se,
    const float* __restrict__ bias, const float* __restrict__ Wg, const float* __restrict__ bg,
    u16* __restrict__ hout, float* __restrict__ gout) {
    int wv = threadIdx.x >> 6;
    int node = blockIdx.x * 4 + wv;
    int lane = threadIdx.x & 63;
    int beg = rowptr[node], end = rowptr[node + 1];
    float4 erv = er4[node];

    __shared__ int    s_off[4][64];
    __shared__ float4 s_p[4][64];

    float S0 = 0.f, S1 = 0.f, S2 = 0.f, S3 = 0.f;
    float a0 = 0.f, a1 = 0.f, a2 = 0.f, a3 = 0.f;

    const char* ftl = (const char*)ft + lane * 8;

    for (int base = beg; base < end; base += 64) {
        int cnt = end - base; if (cnt > 64) cnt = 64;
        if (lane < cnt) {
            int2 se = csr_se[base + lane];
            int sidx = se.x;
            float w = asfloat((unsigned)se.y);
            float4 elv = el4[sidx];
            float t0 = elv.x + erv.x, t1 = elv.y + erv.y, t2 = elv.z + erv.z, t3 = elv.w + erv.w;
            t0 = t0 > 0.f ? t0 : 0.2f * t0;
            t1 = t1 > 0.f ? t1 : 0.2f * t1;
            t2 = t2 > 0.f ? t2 : 0.2f * t2;
            t3 = t3 > 0.f ? t3 : 0.2f * t3;
            float p0 = __expf(fminf(t0, 30.f));
            float p1 = __expf(fminf(t1, 30.f));
            float p2 = __expf(fminf(t2, 30.f));
            float p3 = __expf(fminf(t3, 30.f));
            S0 += p0; S1 += p1; S2 += p2; S3 += p3;
            s_off[wv][lane] = sidx * 512;
            s_p[wv][lane] = make_float4(p0 * w, p1 * w, p2 * w, p3 * w);
        }
        int k = 0;
        for (; k + 4 <= cnt; k += 4) {
            int o0 = s_off[wv][k], o1 = s_off[wv][k + 1], o2 = s_off[wv][k + 2], o3 = s_off[wv][k + 3];
            uint2 r0 = *(const uint2*)(ftl + o0);
            uint2 r1 = *(const uint2*)(ftl + o1);
            uint2 r2 = *(const uint2*)(ftl + o2);
            uint2 r3 = *(const uint2*)(ftl + o3);
            float4 q0 = s_p[wv][k], q1 = s_p[wv][k + 1], q2 = s_p[wv][k + 2], q3 = s_p[wv][k + 3];
            a0 = fmaf(q0.x, asfloat(r0.x << 16), a0);
            a1 = fmaf(q0.y, asfloat(r0.x & 0xffff0000u), a1);
            a2 = fmaf(q0.z, asfloat(r0.y << 16), a2);
            a3 = fmaf(q0.w, asfloat(r0.y & 0xffff0000u), a3);
            a0 = fmaf(q1.x, asfloat(r1.x << 16), a0);
            a1 = fmaf(q1.y, asfloat(r1.x & 0xffff0000u), a1);
            a2 = fmaf(q1.z, asfloat(r1.y << 16), a2);
            a3 = fmaf(q1.w, asfloat(r1.y & 0xffff0000u), a3);
            a0 = fmaf(q2.x, asfloat(r2.x << 16), a0);
            a1 = fmaf(q2.y, asfloat(r2.x & 0xffff0000u), a1);
            a2 = fmaf(q2.z, asfloat(r2.y << 16), a2);
            a3 = fmaf(q2.w, asfloat(r2.y & 0xffff0000u), a3);
            a0 = fmaf(q3.x, asfloat(r3.x << 16), a0);
            a1 = fmaf(q3.y, asfloat(r3.x & 0xffff0000u), a1);
            a2 = fmaf(q3.z, asfloat(r3.y << 16), a2);
            a3 = fmaf(q3.w, asfloat(r3.y & 0xffff0000u), a3);
        }
        for (; k < cnt; k++) {
            int o0 = s_off[wv][k];
            float4 q0 = s_p[wv][k];
            uint2 r0 = *(const uint2*)(ftl + o0);
            a0 = fmaf(q0.x, asfloat(r0.x << 16), a0);
            a1 = fmaf(q0.y, asfloat(r0.x & 0xffff0000u), a1);
            a2 = fmaf(q0.z, asfloat(r0.y << 16), a2);
            a3 = fmaf(q0.w, asfloat(r0.y & 0xffff0000u), a3);
        }
    }
#pragma unroll
    for (int mm = 1; mm < 64; mm <<= 1) {
        S0 += __shfl_xor(S0, mm);
        S1 += __shfl_xor(S1, mm);
        S2 += __shfl_xor(S2, mm);
        S3 += __shfl_xor(S3, mm);
    }
    float i0 = S0 > 0.f ? 1.f / S0 : 0.f;
    float i1 = S1 > 0.f ? 1.f / S1 : 0.f;
    float i2 = S2 > 0.f ? 1.f / S2 : 0.f;
    float i3 = S3 > 0.f ? 1.f / S3 : 0.f;
    float r0 = a0 * i0 + bias[lane];
    float r1 = a1 * i1 + bias[64 + lane];
    float r2 = a2 * i2 + bias[128 + lane];
    float r3 = a3 * i3 + bias[192 + lane];
    float o = (fmaxf(r0, 0.f) + fmaxf(r1, 0.f) + fmaxf(r2, 0.f) + fmaxf(r3, 0.f)) * 0.25f;
    hout[(size_t)node * 64 + lane] = f2bf(o);
    float pg = o * Wg[lane];
#pragma unroll
    for (int mm = 1; mm < 64; mm <<= 1) pg += __shfl_xor(pg, mm);
    if (lane == 0) gout[node] = pg + bg[0];
}

// ---------------- standalone GAP (final layer) ----------------
__global__ __launch_bounds__(256) void k_gapP(const u16* __restrict__ x, const float* __restrict__ g,
                                              const int* __restrict__ gid,
                                              float* __restrict__ pnum, float* __restrict__ pden) {
    gap_part(blockIdx.x, x, g, gid, pnum, pden);
}

// ---------------- LSTM (4 steps) + final linear + sigmoid; combines gap partials ----------------
__global__ __launch_bounds__(256) void k_lstm(const float* __restrict__ pnum, const float* __restrict__ pden,
                                              const float* __restrict__ Wih, const float* __restrict__ Whh,
                                              const float* __restrict__ bih, const float* __restrict__ bhh,
                                              const float* __restrict__ Wc, const float* __restrict__ bc,
                                              float* __restrict__ out) {
    int b = blockIdx.x, t = threadIdx.x;
    __shared__ float h[64], c[64], G[256], xv[64], red[64];
    if (t < 64) { h[t] = 0.f; c[t] = 0.f; }
    __syncthreads();
    for (int step = 0; step < 4; step++) {
        if (t < 64) {
            const float* pn = pnum + (((size_t)step * N_GRAPHS + b) * 8) * 64;
            const float* pd = pden + ((size_t)step * N_GRAPHS + b) * 8;
            float num = 0.f, dn = 0.f;
#pragma unroll
            for (int pp = 0; pp < 8; pp++) { num += pn[pp * 64 + t]; dn += pd[pp]; }
            xv[t] = (dn > 0.f) ? num / dn : 0.f;
        }
        __syncthreads();
        float acc = bih[t] + bhh[t];
#pragma unroll 4
        for (int d = 0; d < 64; d++)
            acc += xv[d] * Wih[t * 64 + d] + h[d] * Whh[t * 64 + d];
        G[t] = acc;
        __syncthreads();
        if (t < 64) {
            float ig = 1.f / (1.f + __expf(-G[t]));
            float fg = 1.f / (1.f + __expf(-G[64 + t]));
            float gg = tanhf(G[128 + t]);
            float og = 1.f / (1.f + __expf(-G[192 + t]));
            float cn = fg * c[t] + ig * gg;
            c[t] = cn;
            h[t] = og * tanhf(cn);
        }
        __syncthreads();
    }
    if (t < 64) red[t] = h[t] * Wc[t];
    __syncthreads();
    if (t == 0) {
        float r = 0.f;
        for (int i = 0; i < 64; i++) r += red[i];
        r += bc[0];
        out[b] = 1.f / (1.f + __expf(-r));
    }
}

extern "C" void kernel_launch(void* const* d_in, const int* in_sizes, int n_in,
                              void* d_out, int out_size, void* d_ws, size_t ws_size,
                              hipStream_t stream) {
    const float* nf   = (const float*)d_in[0];
    const float* nm   = (const float*)d_in[1];
    const float* cent = (const float*)d_in[2];
    const float* ew   = (const float*)d_in[3];
    const int* src  = (const int*)d_in[4];
    const int* dst  = (const int*)d_in[5];
    const int* gid  = (const int*)d_in[6];
    const float* W[3]  = {(const float*)d_in[7],  (const float*)d_in[11], (const float*)d_in[15]};
    const float* al[3] = {(const float*)d_in[8],  (const float*)d_in[12], (const float*)d_in[16]};
    const float* ar[3] = {(const float*)d_in[9],  (const float*)d_in[13], (const float*)d_in[17]};
    const float* bb[3] = {(const float*)d_in[10], (const float*)d_in[14], (const float*)d_in[18]};
    const float* Wg[4] = {(const float*)d_in[19], (const float*)d_in[21], (const float*)d_in[23], (const float*)d_in[25]};
    const float* bg[4] = {(const float*)d_in[20], (const float*)d_in[22], (const float*)d_in[24], (const float*)d_in[26]};
    const float* Wih = (const float*)d_in[27];
    const float* Whh = (const float*)d_in[28];
    const float* bih = (const float*)d_in[29];
    const float* bhh = (const float*)d_in[30];
    const float* Wc  = (const float*)d_in[31];
    const float* bc  = (const float*)d_in[32];
    float* out = (float*)d_out;

    char* p = (char*)d_ws;
    size_t off = 0;
    auto A = [&](size_t bytes) -> char* {
        char* r = p + off;
        off += (bytes + 255) & ~(size_t)255;
        return r;
    };
    u16*   ftb     = (u16*)  A((size_t)N_NODES * 256 * 2);   // 25.6 MB
    u16*   nodebuf = (u16*)  A((size_t)N_NODES * 64 * 2);    // 6.4 MB
    int2*  csr_se  = (int2*) A((size_t)N_EDGES * 8);         // 6.4 MB packed (src, ew)
    float* el      = (float*)A((size_t)N_NODES * 4 * 4);
    float* er      = (float*)A((size_t)N_NODES * 4 * 4);
    float* gbuf    = (float*)A((size_t)N_NODES * 4);
    int*   rowptr  = (int*)  A((size_t)(N_NODES + 1) * 4);
    int*   deg     = (int*)  A((size_t)(N_NODES + 1) * 4);   // becomes scatter cursor
    float* pnum    = (float*)A((size_t)4 * N_GRAPHS * 8 * 64 * 4);
    float* pden    = (float*)A((size_t)4 * N_GRAPHS * 8 * 4);
    int*   bsum    = (int*)  A((size_t)SCAN_B * 4);
    int*   boff    = (int*)  A((size_t)SCAN_B * 4);
    u16*   Wt      = (u16*)  A((size_t)3 * 64 * 256 * 2);

    k_init<<<SCAN_B + N_NODES / 4, 256, 0, stream>>>(nf, nm, cent, Wg[0], bg[0], nodebuf, gbuf, deg);
    k_hist<<<(N_EDGES + 255) / 256, 256, 0, stream>>>(dst, deg);
    k_scanA<<<SCAN_B, 256, 0, stream>>>(deg, rowptr, bsum);
    k_scanBprep<<<13, 256, 0, stream>>>(bsum, boff, W[0], W[1], W[2], Wt);
    k_scanC<<<SCAN_B, 256, 0, stream>>>(boff, rowptr, deg);
    k_scatter<<<(N_EDGES + 255) / 256, 256, 0, stream>>>(src, dst, ew, deg, csr_se);

    for (int l = 0; l < 3; l++) {
        k_ftgap<<<FT_B + GAP_B, 256, 0, stream>>>(nodebuf, Wt + (size_t)l * 64 * 256, al[l], ar[l],
                                                  ftb, el, er, gbuf, gid,
                                                  pnum + (size_t)l * N_GRAPHS * 8 * 64,
                                                  pden + (size_t)l * N_GRAPHS * 8);
        k_agg<<<N_NODES / 4, 256, 0, stream>>>(ftb, (const float4*)el, (const float4*)er, rowptr,
                                               csr_se, bb[l], Wg[l + 1], bg[l + 1], nodebuf, gbuf);
    }
    k_gapP<<<GAP_B, 256, 0, stream>>>(nodebuf, gbuf, gid,
                                      pnum + (size_t)3 * N_GRAPHS * 8 * 64,
                                      pden + (size_t)3 * N_GRAPHS * 8);
    k_lstm<<<N_GRAPHS, 256, 0, stream>>>(pnum, pden, Wih, Whh, bih, bhh, Wc, bc, out);
}

// Round 9
// 444.870 us; speedup vs baseline: 4.5274x; 1.1170x over previous
//
#include <hip/hip_runtime.h>
#include <hip/hip_bf16.h>

#define N_NODES 50000
#define N_EDGES 800000
#define N_GRAPHS 64
#define SCAN_B 196   // ceil(N_NODES/256)
#define FT_B   3125  // N_NODES/16
#define GAP_B  512   // 64 graphs * 8 parts

typedef unsigned short u16;
typedef unsigned char u8;
typedef short s16x8 __attribute__((ext_vector_type(8)));
typedef float f32x4 __attribute__((ext_vector_type(4)));
typedef float f32x2 __attribute__((ext_vector_type(2)));

__device__ __forceinline__ float bf2f(u16 u) {
    union { unsigned int i; float f; } v; v.i = ((unsigned int)u) << 16; return v.f;
}
__device__ __forceinline__ u16 f2bf(float f) {
    union { float f; unsigned int i; } v; v.f = f;
    unsigned int i = v.i;
    unsigned int r = i + 0x7fffu + ((i >> 16) & 1u);
    return (u16)(r >> 16);
}
__device__ __forceinline__ float asfloat(unsigned int u) {
    union { unsigned int i; float f; } v; v.i = u; return v.f;
}

// ---------------- fused: zero deg + (x = concat*centrality, gate logit) ----------------
__global__ __launch_bounds__(256) void k_init(const float* __restrict__ nf, const float* __restrict__ nm,
                                              const float* __restrict__ cent, const float* __restrict__ Wg,
                                              const float* __restrict__ bg,
                                              u16* __restrict__ x, float* __restrict__ g,
                                              int* __restrict__ deg) {
    int b = blockIdx.x;
    if (b < SCAN_B) {                 // zero deg[0..N_NODES]
        int i = b * 256 + threadIdx.x;
        if (i <= N_NODES) deg[i] = 0;
        return;
    }
    b -= SCAN_B;
    int node = b * 4 + (threadIdx.x >> 6);
    int lane = threadIdx.x & 63;
    float v = (lane < 48) ? nf[(size_t)node * 48 + lane] : nm[(size_t)node * 16 + lane - 48];
    float xf = v * cent[node];
    x[(size_t)node * 64 + lane] = f2bf(xf);
    float p = xf * Wg[lane];
#pragma unroll
    for (int mm = 1; mm < 64; mm <<= 1) p += __shfl_xor(p, mm);
    if (lane == 0) g[node] = p + bg[0];
}

// ---------------- CSR build (by dst) ----------------
__global__ __launch_bounds__(256) void k_hist(const int* __restrict__ dst, int* __restrict__ deg) {
    int e = blockIdx.x * 256 + threadIdx.x;
    if (e < N_EDGES) atomicAdd(&deg[dst[e]], 1);
}

__global__ __launch_bounds__(256) void k_scanA(const int* __restrict__ deg,
                                               int* __restrict__ rowptr, int* __restrict__ bsum) {
    int b = blockIdx.x, t = threadIdx.x;
    int i = b * 256 + t;
    int v = (i < N_NODES) ? deg[i] : 0;
    int orig = v;
    int lane = t & 63, w = t >> 6;
#pragma unroll
    for (int d = 1; d < 64; d <<= 1) {
        int u = __shfl_up(v, d);
        if (lane >= d) v += u;
    }
    __shared__ int wsum[4];
    if (lane == 63) wsum[w] = v;
    __syncthreads();
    int add = 0;
    for (int k = 0; k < w; k++) add += wsum[k];
    v += add;
    if (i < N_NODES) rowptr[i] = v - orig;
    if (t == 255) bsum[b] = v;
}

// fused: block 0 = scan of block sums; blocks 1..12 = W transpose (independent)
__global__ __launch_bounds__(256) void k_scanBprep(const int* __restrict__ bsum, int* __restrict__ boff,
                                                   const float* __restrict__ W1, const float* __restrict__ W2,
                                                   const float* __restrict__ W3, u16* __restrict__ Wt) {
    __shared__ float tile[64][65];
    __shared__ int wsum[4];
    if (blockIdx.x == 0) {
        int t = threadIdx.x;
        int v = (t < SCAN_B) ? bsum[t] : 0;
        int orig = v;
        int lane = t & 63, w = t >> 6;
#pragma unroll
        for (int d = 1; d < 64; d <<= 1) {
            int u = __shfl_up(v, d);
            if (lane >= d) v += u;
        }
        if (lane == 63) wsum[w] = v;
        __syncthreads();
        int add = 0;
        for (int k = 0; k < w; k++) add += wsum[k];
        v += add;
        if (t < SCAN_B) boff[t] = v - orig;
        return;
    }
    int bb = blockIdx.x - 1;
    int l = bb >> 2, ti = bb & 3;
    const float* W = (l == 0) ? W1 : (l == 1) ? W2 : W3;
    u16* o = Wt + (size_t)l * 64 * 256;
    int t = threadIdx.x;
    for (int i = t; i < 64 * 64; i += 256) {
        int d = i >> 6, c = i & 63;
        tile[d][c] = W[d * 256 + ti * 64 + c];
    }
    __syncthreads();
    for (int i = t; i < 64 * 64; i += 256) {
        int c = i >> 6, d = i & 63;
        o[(size_t)(ti * 64 + c) * 64 + d] = f2bf(tile[d][c]);
    }
}

__global__ __launch_bounds__(256) void k_scanC(const int* __restrict__ boff,
                                               int* __restrict__ rowptr, int* __restrict__ deg) {
    int b = blockIdx.x, t = threadIdx.x;
    int i = b * 256 + t;
    if (i < N_NODES) {
        int val = rowptr[i] + boff[b];
        int d = deg[i];
        rowptr[i] = val;
        deg[i] = val;
        if (i == N_NODES - 1) rowptr[N_NODES] = val + d;
    }
}

// packed (src, ew) scatter: ONE 8B random write per edge
__global__ __launch_bounds__(256) void k_scatter(const int* __restrict__ src, const int* __restrict__ dst,
                                                 const float* __restrict__ ew, int* __restrict__ cursor,
                                                 int2* __restrict__ csr_se) {
    int e = blockIdx.x * 256 + threadIdx.x;
    if (e < N_EDGES) {
        int d = dst[e];
        int pos = atomicAdd(&cursor[d], 1);
        csr_se[pos] = make_int2(src[e], __float_as_int(ew[e]));
    }
}

// ---------------- GAP partial (device fn): 8 parts/graph, no-max exp ----------------
__device__ __forceinline__ void gap_part(int pb, const u16* __restrict__ x, const float* __restrict__ g,
                                         const int* __restrict__ gid,
                                         float* __restrict__ pnum, float* __restrict__ pden) {
    int part = pb & 7, b = pb >> 3;
    int t = threadIdx.x, w = t >> 6, lane = t & 63, q = lane >> 4, c = lane & 15;
    int lo = 0, hi = N_NODES;
    while (lo < hi) { int mid = (lo + hi) >> 1; if (gid[mid] < b) lo = mid + 1; else hi = mid; }
    int s = lo;
    lo = 0; hi = N_NODES;
    while (lo < hi) { int mid = (lo + hi) >> 1; if (gid[mid] < b + 1) lo = mid + 1; else hi = mid; }
    int e = lo;
    int len = e - s;
    int ps = s + (int)(((long long)len * part) >> 3);
    int pe = s + (int)(((long long)len * (part + 1)) >> 3);

    float a0 = 0.f, a1 = 0.f, a2 = 0.f, a3 = 0.f, den = 0.f;
    for (int n0 = ps + w * 4; n0 < pe; n0 += 16) {
        int node = n0 + q;
        if (node < pe) {
            float gate = __expf(fminf(g[node], 30.f));
            uint2 raw = *(const uint2*)(x + (size_t)node * 64 + c * 4);
            a0 = fmaf(gate, asfloat(raw.x << 16), a0);
            a1 = fmaf(gate, asfloat(raw.x & 0xffff0000u), a1);
            a2 = fmaf(gate, asfloat(raw.y << 16), a2);
            a3 = fmaf(gate, asfloat(raw.y & 0xffff0000u), a3);
            if (c == 0) den += gate;
        }
    }
#pragma unroll
    for (int mm = 16; mm < 64; mm <<= 1) {
        a0 += __shfl_xor(a0, mm); a1 += __shfl_xor(a1, mm);
        a2 += __shfl_xor(a2, mm); a3 += __shfl_xor(a3, mm);
        den += __shfl_xor(den, mm);
    }
    __shared__ float snum[4][64];
    __shared__ float sden[4];
    if (lane < 16) {
        snum[w][c * 4 + 0] = a0; snum[w][c * 4 + 1] = a1;
        snum[w][c * 4 + 2] = a2; snum[w][c * 4 + 3] = a3;
        if (lane == 0) sden[w] = den;
    }
    __syncthreads();
    if (t < 64) pnum[((size_t)b * 8 + part) * 64 + t] = snum[0][t] + snum[1][t] + snum[2][t] + snum[3][t];
    if (t == 0) pden[b * 8 + part] = sden[0] + sden[1] + sden[2] + sden[3];
}

// ---------------- fused: ft = X @ W (MFMA, fp8 output) + el/er  |  GAP partials ----------------
__global__ __launch_bounds__(256) void k_ftgap(const u16* __restrict__ X, const u16* __restrict__ Wt,
                                               const float* __restrict__ al, const float* __restrict__ ar,
                                               u8* __restrict__ ft, float* __restrict__ el, float* __restrict__ er,
                                               const float* __restrict__ g, const int* __restrict__ gid,
                                               float* __restrict__ pnum, float* __restrict__ pden) {
    if (blockIdx.x >= FT_B) {
        gap_part(blockIdx.x - FT_B, X, g, gid, pnum, pden);
        return;
    }
    int w = threadIdx.x >> 6;
    int lane = threadIdx.x & 63;
    int quad = lane >> 4, c = lane & 15;
    int n0 = blockIdx.x * 16;

    f32x4 acc[4];
#pragma unroll
    for (int t = 0; t < 4; t++) acc[t] = (f32x4){0.f, 0.f, 0.f, 0.f};

#pragma unroll
    for (int kh = 0; kh < 2; kh++) {
        s16x8 a = *(const s16x8*)(X + (size_t)(n0 + c) * 64 + kh * 32 + quad * 8);
#pragma unroll
        for (int t = 0; t < 4; t++) {
            int col = w * 64 + t * 16 + c;
            s16x8 b = *(const s16x8*)(Wt + (size_t)col * 64 + kh * 32 + quad * 8);
            acc[t] = __builtin_amdgcn_mfma_f32_16x16x32_bf16(a, b, acc[t], 0, 0, 0);
        }
    }

    // el/er from f32 accumulators (quantization does NOT touch attention logits)
    __shared__ u8 sft[16 * 256];   // fp8 tile
    float alv[4], arv[4];
#pragma unroll
    for (int t = 0; t < 4; t++) {
        alv[t] = al[w * 64 + t * 16 + c];
        arv[t] = ar[w * 64 + t * 16 + c];
    }
    float pel[4] = {0.f, 0.f, 0.f, 0.f}, per[4] = {0.f, 0.f, 0.f, 0.f};
#pragma unroll
    for (int t = 0; t < 4; t++) {
#pragma unroll
        for (int r = 0; r < 4; r++) {
            float v = acc[t][r];
            int nl = quad * 4 + r;
            int d = t * 16 + c;
            int pk = __builtin_amdgcn_cvt_pk_fp8_f32(v, v, 0, false);
            sft[nl * 256 + d * 4 + w] = (u8)(pk & 0xff);
            pel[r] += v * alv[t];
            per[r] += v * arv[t];
        }
    }
#pragma unroll
    for (int r = 0; r < 4; r++) {
#pragma unroll
        for (int mm = 1; mm < 16; mm <<= 1) {
            pel[r] += __shfl_xor(pel[r], mm);
            per[r] += __shfl_xor(per[r], mm);
        }
    }
    if (c == 0) {
#pragma unroll
        for (int r = 0; r < 4; r++) {
            int node = n0 + quad * 4 + r;
            el[node * 4 + w] = pel[r];
            er[node * 4 + w] = per[r];
        }
    }
    __syncthreads();
    // coalesced store: 4 KB tile = 256 threads x 16 B
    const uint4* s4 = (const uint4*)sft;
    uint4* g4 = (uint4*)(ft + (size_t)n0 * 256);
    g4[threadIdx.x] = s4[threadIdx.x];
}

// ---------------- per-dst-node edge softmax + aggregation (wave per node, fp8 gather) ----------------
__global__ __launch_bounds__(256) void k_agg(
    const u8* __restrict__ ft, const float4* __restrict__ el4, const float4* __restrict__ er4,
    const int* __restrict__ rowptr, const int2* __restrict__ csr_se,
    const float* __restrict__ bias, const float* __restrict__ Wg, const float* __restrict__ bg,
    u16* __restrict__ hout, float* __restrict__ gout) {
    int wv = threadIdx.x >> 6;
    int node = blockIdx.x * 4 + wv;
    int lane = threadIdx.x & 63;
    int beg = rowptr[node], end = rowptr[node + 1];
    float4 erv = er4[node];

    __shared__ int    s_off[4][64];
    __shared__ float4 s_p[4][64];

    float S0 = 0.f, S1 = 0.f, S2 = 0.f, S3 = 0.f;
    float a0 = 0.f, a1 = 0.f, a2 = 0.f, a3 = 0.f;

    const char* ftl = (const char*)ft + lane * 4;

    for (int base = beg; base < end; base += 64) {
        int cnt = end - base; if (cnt > 64) cnt = 64;
        if (lane < cnt) {
            int2 se = csr_se[base + lane];
            int sidx = se.x;
            float w = asfloat((unsigned)se.y);
            float4 elv = el4[sidx];
            float t0 = elv.x + erv.x, t1 = elv.y + erv.y, t2 = elv.z + erv.z, t3 = elv.w + erv.w;
            t0 = t0 > 0.f ? t0 : 0.2f * t0;
            t1 = t1 > 0.f ? t1 : 0.2f * t1;
            t2 = t2 > 0.f ? t2 : 0.2f * t2;
            t3 = t3 > 0.f ? t3 : 0.2f * t3;
            float p0 = __expf(fminf(t0, 30.f));
            float p1 = __expf(fminf(t1, 30.f));
            float p2 = __expf(fminf(t2, 30.f));
            float p3 = __expf(fminf(t3, 30.f));
            S0 += p0; S1 += p1; S2 += p2; S3 += p3;
            s_off[wv][lane] = sidx * 256;
            s_p[wv][lane] = make_float4(p0 * w, p1 * w, p2 * w, p3 * w);
        }
        int k = 0;
        for (; k + 4 <= cnt; k += 4) {
            int o0 = s_off[wv][k], o1 = s_off[wv][k + 1], o2 = s_off[wv][k + 2], o3 = s_off[wv][k + 3];
            unsigned r0 = *(const unsigned*)(ftl + o0);
            unsigned r1 = *(const unsigned*)(ftl + o1);
            unsigned r2 = *(const unsigned*)(ftl + o2);
            unsigned r3 = *(const unsigned*)(ftl + o3);
            float4 q0 = s_p[wv][k], q1 = s_p[wv][k + 1], q2 = s_p[wv][k + 2], q3 = s_p[wv][k + 3];
            f32x2 l0 = __builtin_amdgcn_cvt_pk_f32_fp8(r0, false), h0 = __builtin_amdgcn_cvt_pk_f32_fp8(r0, true);
            f32x2 l1 = __builtin_amdgcn_cvt_pk_f32_fp8(r1, false), h1 = __builtin_amdgcn_cvt_pk_f32_fp8(r1, true);
            f32x2 l2 = __builtin_amdgcn_cvt_pk_f32_fp8(r2, false), h2 = __builtin_amdgcn_cvt_pk_f32_fp8(r2, true);
            f32x2 l3 = __builtin_amdgcn_cvt_pk_f32_fp8(r3, false), h3 = __builtin_amdgcn_cvt_pk_f32_fp8(r3, true);
            a0 = fmaf(q0.x, l0.x, a0); a1 = fmaf(q0.y, l0.y, a1);
            a2 = fmaf(q0.z, h0.x, a2); a3 = fmaf(q0.w, h0.y, a3);
            a0 = fmaf(q1.x, l1.x, a0); a1 = fmaf(q1.y, l1.y, a1);
            a2 = fmaf(q1.z, h1.x, a2); a3 = fmaf(q1.w, h1.y, a3);
            a0 = fmaf(q2.x, l2.x, a0); a1 = fmaf(q2.y, l2.y, a1);
            a2 = fmaf(q2.z, h2.x, a2); a3 = fmaf(q2.w, h2.y, a3);
            a0 = fmaf(q3.x, l3.x, a0); a1 = fmaf(q3.y, l3.y, a1);
            a2 = fmaf(q3.z, h3.x, a2); a3 = fmaf(q3.w, h3.y, a3);
        }
        for (; k < cnt; k++) {
            int o0 = s_off[wv][k];
            float4 q0 = s_p[wv][k];
            unsigned r0 = *(const unsigned*)(ftl + o0);
            f32x2 l0 = __builtin_amdgcn_cvt_pk_f32_fp8(r0, false), h0 = __builtin_amdgcn_cvt_pk_f32_fp8(r0, true);
            a0 = fmaf(q0.x, l0.x, a0); a1 = fmaf(q0.y, l0.y, a1);
            a2 = fmaf(q0.z, h0.x, a2); a3 = fmaf(q0.w, h0.y, a3);
        }
    }
#pragma unroll
    for (int mm = 1; mm < 64; mm <<= 1) {
        S0 += __shfl_xor(S0, mm);
        S1 += __shfl_xor(S1, mm);
        S2 += __shfl_xor(S2, mm);
        S3 += __shfl_xor(S3, mm);
    }
    float i0 = S0 > 0.f ? 1.f / S0 : 0.f;
    float i1 = S1 > 0.f ? 1.f / S1 : 0.f;
    float i2 = S2 > 0.f ? 1.f / S2 : 0.f;
    float i3 = S3 > 0.f ? 1.f / S3 : 0.f;
    float r0 = a0 * i0 + bias[lane];
    float r1 = a1 * i1 + bias[64 + lane];
    float r2 = a2 * i2 + bias[128 + lane];
    float r3 = a3 * i3 + bias[192 + lane];
    float o = (fmaxf(r0, 0.f) + fmaxf(r1, 0.f) + fmaxf(r2, 0.f) + fmaxf(r3, 0.f)) * 0.25f;
    hout[(size_t)node * 64 + lane] = f2bf(o);
    float pg = o * Wg[lane];
#pragma unroll
    for (int mm = 1; mm < 64; mm <<= 1) pg += __shfl_xor(pg, mm);
    if (lane == 0) gout[node] = pg + bg[0];
}

// ---------------- standalone GAP (final layer) ----------------
__global__ __launch_bounds__(256) void k_gapP(const u16* __restrict__ x, const float* __restrict__ g,
                                              const int* __restrict__ gid,
                                              float* __restrict__ pnum, float* __restrict__ pden) {
    gap_part(blockIdx.x, x, g, gid, pnum, pden);
}

// ---------------- LSTM (4 steps) + final linear + sigmoid; combines gap partials ----------------
__global__ __launch_bounds__(256) void k_lstm(const float* __restrict__ pnum, const float* __restrict__ pden,
                                              const float* __restrict__ Wih, const float* __restrict__ Whh,
                                              const float* __restrict__ bih, const float* __restrict__ bhh,
                                              const float* __restrict__ Wc, const float* __restrict__ bc,
                                              float* __restrict__ out) {
    int b = blockIdx.x, t = threadIdx.x;
    __shared__ float h[64], c[64], G[256], xv[64], red[64];
    if (t < 64) { h[t] = 0.f; c[t] = 0.f; }
    __syncthreads();
    for (int step = 0; step < 4; step++) {
        if (t < 64) {
            const float* pn = pnum + (((size_t)step * N_GRAPHS + b) * 8) * 64;
            const float* pd = pden + ((size_t)step * N_GRAPHS + b) * 8;
            float num = 0.f, dn = 0.f;
#pragma unroll
            for (int pp = 0; pp < 8; pp++) { num += pn[pp * 64 + t]; dn += pd[pp]; }
            xv[t] = (dn > 0.f) ? num / dn : 0.f;
        }
        __syncthreads();
        float acc = bih[t] + bhh[t];
#pragma unroll 4
        for (int d = 0; d < 64; d++)
            acc += xv[d] * Wih[t * 64 + d] + h[d] * Whh[t * 64 + d];
        G[t] = acc;
        __syncthreads();
        if (t < 64) {
            float ig = 1.f / (1.f + __expf(-G[t]));
            float fg = 1.f / (1.f + __expf(-G[64 + t]));
            float gg = tanhf(G[128 + t]);
            float og = 1.f / (1.f + __expf(-G[192 + t]));
            float cn = fg * c[t] + ig * gg;
            c[t] = cn;
            h[t] = og * tanhf(cn);
        }
        __syncthreads();
    }
    if (t < 64) red[t] = h[t] * Wc[t];
    __syncthreads();
    if (t == 0) {
        float r = 0.f;
        for (int i = 0; i < 64; i++) r += red[i];
        r += bc[0];
        out[b] = 1.f / (1.f + __expf(-r));
    }
}

extern "C" void kernel_launch(void* const* d_in, const int* in_sizes, int n_in,
                              void* d_out, int out_size, void* d_ws, size_t ws_size,
                              hipStream_t stream) {
    const float* nf   = (const float*)d_in[0];
    const float* nm   = (const float*)d_in[1];
    const float* cent = (const float*)d_in[2];
    const float* ew   = (const float*)d_in[3];
    const int* src  = (const int*)d_in[4];
    const int* dst  = (const int*)d_in[5];
    const int* gid  = (const int*)d_in[6];
    const float* W[3]  = {(const float*)d_in[7],  (const float*)d_in[11], (const float*)d_in[15]};
    const float* al[3] = {(const float*)d_in[8],  (const float*)d_in[12], (const float*)d_in[16]};
    const float* ar[3] = {(const float*)d_in[9],  (const float*)d_in[13], (const float*)d_in[17]};
    const float* bb[3] = {(const float*)d_in[10], (const float*)d_in[14], (const float*)d_in[18]};
    const float* Wg[4] = {(const float*)d_in[19], (const float*)d_in[21], (const float*)d_in[23], (const float*)d_in[25]};
    const float* bg[4] = {(const float*)d_in[20], (const float*)d_in[22], (const float*)d_in[24], (const float*)d_in[26]};
    const float* Wih = (const float*)d_in[27];
    const float* Whh = (const float*)d_in[28];
    const float* bih = (const float*)d_in[29];
    const float* bhh = (const float*)d_in[30];
    const float* Wc  = (const float*)d_in[31];
    const float* bc  = (const float*)d_in[32];
    float* out = (float*)d_out;

    char* p = (char*)d_ws;
    size_t off = 0;
    auto A = [&](size_t bytes) -> char* {
        char* r = p + off;
        off += (bytes + 255) & ~(size_t)255;
        return r;
    };
    u8*    ftb     = (u8*)   A((size_t)N_NODES * 256);       // 12.8 MB fp8
    u16*   nodebuf = (u16*)  A((size_t)N_NODES * 64 * 2);    // 6.4 MB
    int2*  csr_se  = (int2*) A((size_t)N_EDGES * 8);         // 6.4 MB packed (src, ew)
    float* el      = (float*)A((size_t)N_NODES * 4 * 4);
    float* er      = (float*)A((size_t)N_NODES * 4 * 4);
    float* gbuf    = (float*)A((size_t)N_NODES * 4);
    int*   rowptr  = (int*)  A((size_t)(N_NODES + 1) * 4);
    int*   deg     = (int*)  A((size_t)(N_NODES + 1) * 4);   // becomes scatter cursor
    float* pnum    = (float*)A((size_t)4 * N_GRAPHS * 8 * 64 * 4);
    float* pden    = (float*)A((size_t)4 * N_GRAPHS * 8 * 4);
    int*   bsum    = (int*)  A((size_t)SCAN_B * 4);
    int*   boff    = (int*)  A((size_t)SCAN_B * 4);
    u16*   Wt      = (u16*)  A((size_t)3 * 64 * 256 * 2);

    k_init<<<SCAN_B + N_NODES / 4, 256, 0, stream>>>(nf, nm, cent, Wg[0], bg[0], nodebuf, gbuf, deg);
    k_hist<<<(N_EDGES + 255) / 256, 256, 0, stream>>>(dst, deg);
    k_scanA<<<SCAN_B, 256, 0, stream>>>(deg, rowptr, bsum);
    k_scanBprep<<<13, 256, 0, stream>>>(bsum, boff, W[0], W[1], W[2], Wt);
    k_scanC<<<SCAN_B, 256, 0, stream>>>(boff, rowptr, deg);
    k_scatter<<<(N_EDGES + 255) / 256, 256, 0, stream>>>(src, dst, ew, deg, csr_se);

    for (int l = 0; l < 3; l++) {
        k_ftgap<<<FT_B + GAP_B, 256, 0, stream>>>(nodebuf, Wt + (size_t)l * 64 * 256, al[l], ar[l],
                                                  ftb, el, er, gbuf, gid,
                                                  pnum + (size_t)l * N_GRAPHS * 8 * 64,
                                                  pden + (size_t)l * N_GRAPHS * 8);
        k_agg<<<N_NODES / 4, 256, 0, stream>>>(ftb, (const float4*)el, (const float4*)er, rowptr,
                                               csr_se, bb[l], Wg[l + 1], bg[l + 1], nodebuf, gbuf);
    }
    k_gapP<<<GAP_B, 256, 0, stream>>>(nodebuf, gbuf, gid,
                                      pnum + (size_t)3 * N_GRAPHS * 8 * 64,
                                      pden + (size_t)3 * N_GRAPHS * 8);
    k_lstm<<<N_GRAPHS, 256, 0, stream>>>(pnum, pden, Wih, Whh, bih, bhh, Wc, bc, out);
}